// Round 5
// baseline (541.056 us; speedup 1.0000x reference)
//
#include <hip/hip_runtime.h>
#include <math.h>

typedef unsigned short u16;
typedef __attribute__((ext_vector_type(4))) float f32x4;
typedef __attribute__((ext_vector_type(8))) short bf16x8;
typedef __attribute__((ext_vector_type(4))) unsigned short u16x4;
typedef __attribute__((ext_vector_type(8))) unsigned short u16x8;

#define DEVI static __device__ __forceinline__

DEVI float b2f(u16 u){ union{float f; unsigned i;} v; v.i = ((unsigned)u)<<16; return v.f; }
DEVI u16 f2b(float f){ union{float f; unsigned i;} v; v.f=f;
  unsigned r = v.i + 0x7fffu + ((v.i>>16)&1u); return (u16)(r>>16); }

DEVI void gload_lds16(const void* g, void* l){
  __builtin_amdgcn_global_load_lds((const __attribute__((address_space(1))) void*)g,
                                   (__attribute__((address_space(3))) void*)l, 16, 0, 0);
}

DEVI f32x4 vmax4(f32x4 a, f32x4 b){
  f32x4 r; r[0]=fmaxf(a[0],b[0]); r[1]=fmaxf(a[1],b[1]);
  r[2]=fmaxf(a[2],b[2]); r[3]=fmaxf(a[3],b[3]); return r;
}

// ---------------------------------------------------------------------------
// W (512x512 f32, [k][c]) -> swizzled bf16 Wt[c][k]: row c 1024B, granule
// g=k>>3 stored at g^(c&15), byte (k&7)*2.
__global__ void prepw_k(const float* __restrict__ W, u16* __restrict__ Wt){
  int id = blockIdx.x*256 + threadIdx.x;
  int k = id>>9, c = id&511;
  Wt[c*512 + (((k>>3)^(c&15))<<3) + (k&7)] = f2b(W[id]);
}

// f32 [nrows][512] -> linear bf16 + row norms (for centroids feeding pdist)
__global__ void cvt_k(const float* __restrict__ src, u16* __restrict__ dst,
                      float* __restrict__ norms, int nrows){
  int gw = (int)((blockIdx.x*blockDim.x + threadIdx.x)>>6);
  int lane = threadIdx.x & 63;
  if (gw >= nrows) return;
  const float* s = src + (size_t)gw*512;
  u16* d = dst + (size_t)gw*512;
  float acc = 0.f;
  #pragma unroll
  for (int q=0;q<2;q++){
    f32x4 v = *(const f32x4*)(s + q*256 + lane*4);
    u16x4 u;
    #pragma unroll
    for (int e=0;e<4;e++){
      u16 b = f2b(v[e]); u[e] = b;
      float fv = b2f(b); acc += fv*fv;
    }
    *(u16x4*)(d + q*256 + lane*4) = u;
  }
  #pragma unroll
  for (int off=1;off<64;off<<=1) acc += __shfl_xor(acc, off);
  if (lane==0) norms[gw] = acc;
}

// ---------------------------------------------------------------------------
// Fused MLP: P = relu(X@W1+b1)@W2+b2 (bf16 out) + row norms of bf16(P).
// 64-row tiles, X f32 read directly into register A-fragments, H in LDS.
__global__ __launch_bounds__(512) void mlp_k(
    const float* __restrict__ sq, const float* __restrict__ sr,
    const u16* __restrict__ W1S, const u16* __restrict__ W2S,
    const float* __restrict__ b1, const float* __restrict__ b2,
    u16* __restrict__ P, float* __restrict__ NP)
{
  __shared__ __align__(16) u16 sW[2][16384];  // 32 cols x 512 k (swizzled rows)
  __shared__ __align__(16) u16 sH[64*512];    // 64 x 512 bf16, swizzled rows
  __shared__ float sB1[512], sB2[512];
  __shared__ float npart[8][16];

  const int tid = threadIdx.x, w = tid>>6, lane = tid&63;
  const int l15 = lane&15, lg = lane>>4;
  const int rt = w>>1, par = w&1;
  const int row0 = blockIdx.x*64;
  const float* Xb = (blockIdx.x < 512) ? sq + (size_t)row0*512
                                       : sr + (size_t)(row0-32768)*512;
  if (tid<512){ sB1[tid] = b1[tid]; sB2[tid] = b2[tid]; }

  // A-fragments: rows 16rt+l15, k-slice 32kc+8lg (f32 -> bf16 in reg)
  bf16x8 Xfr[16];
  {
    const float* xr = Xb + (size_t)(16*rt + l15)*512;
    #pragma unroll
    for (int kc=0;kc<16;kc++){
      f32x4 a = *(const f32x4*)(xr + 32*kc + 8*lg);
      f32x4 c2 = *(const f32x4*)(xr + 32*kc + 8*lg + 4);
      u16x8 t;
      t[0]=f2b(a[0]); t[1]=f2b(a[1]); t[2]=f2b(a[2]); t[3]=f2b(a[3]);
      t[4]=f2b(c2[0]); t[5]=f2b(c2[1]); t[6]=f2b(c2[2]); t[7]=f2b(c2[3]);
      Xfr[kc] = *(bf16x8*)&t;
    }
  }

  // ---- GEMM1: H = relu(X@W1+b1) -> sH
  #pragma unroll
  for (int i=0;i<4;i++)
    gload_lds16((const char*)W1S + i*8192 + tid*16, (char*)sW[0] + i*8192 + tid*16);
  __syncthreads();
  for (int p=0;p<16;p++){
    if (p<15){
      #pragma unroll
      for (int i=0;i<4;i++)
        gload_lds16((const char*)W1S + (p+1)*32768 + i*8192 + tid*16,
                    (char*)sW[(p+1)&1] + i*8192 + tid*16);
    }
    f32x4 acc = {0.f,0.f,0.f,0.f};
    const u16* bw = sW[p&1] + (16*par + l15)*512;
    #pragma unroll
    for (int kc=0;kc<16;kc++){
      bf16x8 bf = *(const bf16x8*)(bw + (((4*kc+lg)^l15)<<3));
      acc = __builtin_amdgcn_mfma_f32_16x16x32_bf16(Xfr[kc], bf, acc, 0,0,0);
    }
    const int c = 32*p + 16*par + l15;
    const float bv = sB1[c];
    #pragma unroll
    for (int r=0;r<4;r++){
      float h = fmaxf(acc[r]+bv, 0.f);
      const int m = 16*rt + 4*lg + r;
      sH[m*512 + (((c>>3)^(m&15))<<3) + (c&7)] = f2b(h);
    }
    __syncthreads();
  }

  // ---- GEMM2: P = H@W2+b2 -> global (+ norms)
  f32x4 nacc = {0.f,0.f,0.f,0.f};
  #pragma unroll
  for (int i=0;i<4;i++)
    gload_lds16((const char*)W2S + i*8192 + tid*16, (char*)sW[0] + i*8192 + tid*16);
  __syncthreads();
  for (int p=0;p<16;p++){
    if (p<15){
      #pragma unroll
      for (int i=0;i<4;i++)
        gload_lds16((const char*)W2S + (p+1)*32768 + i*8192 + tid*16,
                    (char*)sW[(p+1)&1] + i*8192 + tid*16);
    }
    f32x4 acc = {0.f,0.f,0.f,0.f};
    const u16* bw = sW[p&1] + (16*par + l15)*512;
    const u16* ar = sH + (16*rt + l15)*512;
    #pragma unroll
    for (int kc=0;kc<16;kc++){
      bf16x8 af = *(const bf16x8*)(ar + (((4*kc+lg)^l15)<<3));
      bf16x8 bf = *(const bf16x8*)(bw + (((4*kc+lg)^l15)<<3));
      acc = __builtin_amdgcn_mfma_f32_16x16x32_bf16(af, bf, acc, 0,0,0);
    }
    const int c = 32*p + 16*par + l15;
    const float bv = sB2[c];
    #pragma unroll
    for (int r=0;r<4;r++){
      float pv = acc[r]+bv;
      u16 pb = f2b(pv);
      const int m = 16*rt + 4*lg + r;
      P[(size_t)(row0+m)*512 + c] = pb;
      float fv = b2f(pb);
      nacc[r] += fv*fv;
    }
    __syncthreads();
  }
  #pragma unroll
  for (int off=1;off<16;off<<=1){
    nacc[0] += __shfl_xor(nacc[0],off); nacc[1] += __shfl_xor(nacc[1],off);
    nacc[2] += __shfl_xor(nacc[2],off); nacc[3] += __shfl_xor(nacc[3],off);
  }
  if (l15==0) *(f32x4*)&npart[w][4*lg] = nacc;
  __syncthreads();
  if (tid<64){
    int rt2 = tid>>4, m = tid&15;
    NP[row0 + 16*rt2 + m] = npart[2*rt2][m] + npart[2*rt2+1][m];
  }
}

// pdist: MODE 0 -> OUT f32 [b][k][m]. MODE 1 -> S2t f32 plane + SHL hi/lo bf16
// planes, transposed + XOR-granule-swizzled (key = planerow&15).
template<int MODE>
__global__ __launch_bounds__(256) void pdist_k(const u16* __restrict__ Xa,
    const u16* __restrict__ Xb2, const float* __restrict__ na, const float* __restrict__ nb,
    float* __restrict__ OUT, float* __restrict__ S2t, char* __restrict__ SHL){
  __shared__ __align__(16) u16 sA[128*64];
  __shared__ __align__(16) u16 sB[128*64];
  const int tid = threadIdx.x, wave = tid>>6, lane = tid&63;
  const int b = blockIdx.x;
  const u16* Ab = Xa + (size_t)b*(128*512);
  const u16* Bb = Xb2 + (size_t)b*(128*512);
  const int lrow = lane&15, lg = lane>>4, wr = wave>>1, wc = wave&1;
  f32x4 acc[4][4] = {};
  for (int s=0;s<8;s++){
    const int k0 = s<<6;
    #pragma unroll
    for (int q=0;q<4;q++){
      const int i = (wave<<2)+q;
      const int row = (i<<3) + (lane>>3);
      const int cd = (lane&7) ^ (row&7);
      gload_lds16(Ab + row*512 + k0 + (cd<<3), sA + i*512);
      gload_lds16(Bb + row*512 + k0 + (cd<<3), sB + i*512);
    }
    __syncthreads();
    #pragma unroll
    for (int kh=0;kh<2;kh++){
      bf16x8 a_[4], b_[4];
      #pragma unroll
      for (int i=0;i<4;i++){
        const int ra = (wr<<6)+(i<<4)+lrow;
        a_[i] = *(const bf16x8*)(sA + ra*64 + ((((kh<<2)+lg)^(ra&7))<<3));
        const int rb = (wc<<6)+(i<<4)+lrow;
        b_[i] = *(const bf16x8*)(sB + rb*64 + ((((kh<<2)+lg)^(rb&7))<<3));
      }
      #pragma unroll
      for (int i=0;i<4;i++)
        #pragma unroll
        for (int j=0;j<4;j++)
          acc[i][j] = __builtin_amdgcn_mfma_f32_16x16x32_bf16(a_[i], b_[j], acc[i][j], 0,0,0);
    }
    __syncthreads();
  }
  #pragma unroll
  for (int j=0;j<4;j++){
    const int col = (wc<<6)+(j<<4)+lrow;
    const float nbv = nb[b*128+col];
    #pragma unroll
    for (int i=0;i<4;i++){
      const int row0 = (wr<<6)+(i<<4)+(lg<<2);
      float sv[4];
      #pragma unroll
      for (int r=0;r<4;r++){
        float n2 = na[b*128+row0+r] + nbv - 2.0f*acc[i][j][r];
        sv[r] = sqrtf(fmaxf(n2, 1e-6f));
      }
      if (MODE==0){
        #pragma unroll
        for (int r=0;r<4;r++)
          OUT[(size_t)b*16384 + (size_t)(row0+r)*128 + col] = sv[r];
      } else {
        u16x4 hi4, lo4; f32x4 s2q;
        #pragma unroll
        for (int r=0;r<4;r++){
          u16 h = f2b(sv[r]); hi4[r] = h;
          lo4[r] = f2b(sv[r] - b2f(h));
          s2q[r] = sv[r]*sv[r];
        }
        const int sa = col*256 + ((((row0>>3)^col)&15)<<4) + ((row0&7)<<1);
        char* base = SHL + (size_t)b*65536;
        *(u16x4*)(base + sa) = hi4;
        *(u16x4*)(base + 32768 + sa) = lo4;
        *(f32x4*)(S2t + (size_t)b*16384 + col*128 + row0) = s2q;
      }
    }
  }
}

// ---------------------------------------------------------------------------
// mu/nu + base-2 logs. 256 blocks x 128 threads.
__global__ void prep_k(const float* __restrict__ mask_q, const float* __restrict__ mask_r,
                       float* __restrict__ lmu2, float* __restrict__ lnu2,
                       float* __restrict__ mu, float* __restrict__ nu){
  int b = blockIdx.x, t = threadIdx.x;
  __shared__ float red[4];
  float mq = mask_q[b*128+t], mr = mask_r[b*128+t];
  float s1 = mq, s2 = mr;
  #pragma unroll
  for (int off=1;off<64;off<<=1){ s1 += __shfl_xor(s1,off); s2 += __shfl_xor(s2,off); }
  if ((t&63)==0){ red[t>>6] = s1; red[2+(t>>6)] = s2; }
  __syncthreads();
  float sumq = red[0]+red[1], sumr = red[2]+red[3];
  float muv = mq/(sumq+1e-8f), nuv = mr/(sumr+1e-8f);
  lmu2[b*128+t] = __log2f(fmaxf(muv,1e-8f));
  lnu2[b*128+t] = __log2f(fmaxf(nuv,1e-8f));
  mu[b*128+t] = muv;
  nu[b*128+t] = nuv;
}

// ---------------------------------------------------------------------------
// 5-iter FGW loop, 1024 threads/block (16 waves = 4/SIMD), base-2 domain.
// MFMA: wave w -> A-tile at=w>>1, B-tiles 4*(w&1)+j.
// Sinkhorn: Layout-R thread owns row kR=8w+(lane&7), cols [16p8,16p8+16);
//           Layout-C symmetric.
__global__ __launch_bounds__(1024,1) void fgw_loop_k(
    const char* __restrict__ SQHL, const char* __restrict__ SRHL,
    const float* __restrict__ SQ2, const float* __restrict__ SR2,
    const float* __restrict__ C_g,
    const float* __restrict__ MU, const float* __restrict__ NU,
    const float* __restrict__ LMU2, const float* __restrict__ LNU2,
    const float* __restrict__ log_eps,
    float* __restrict__ T_out, float* __restrict__ cost_out, float* __restrict__ sim_out)
{
  __shared__ __align__(16) char bufT[65536];
  __shared__ __align__(16) char bufS[65536];
  __shared__ __align__(16) float avs[128], bvs[128], t1s[128], t2s[128];
  __shared__ __align__(16) float lus[128], lvs[128];
  __shared__ float redc[16];

  const int b = blockIdx.x, tid = threadIdx.x;
  const int w = tid>>6, lane = tid&63, l15 = lane&15, lg = lane>>4;
  const int l7 = lane&7, p8 = lane>>3;
  const int at = w>>1, par = w&1;
  const char* SqHLb = SQHL + (size_t)b*65536;
  const char* SrHLb = SRHL + (size_t)b*65536;
  const float* Sq2b = SQ2 + (size_t)b*16384;
  const float* Sr2b = SR2 + (size_t)b*16384;
  const float* Cb   = C_g + (size_t)b*16384;
  const float* MUb  = MU + b*128;
  const float* NUb  = NU + b*128;

  float eps = __expf(log_eps[0]); eps = fminf(fmaxf(eps,0.01f),0.5f);
  const float rho = 0.1f/(0.1f+eps);
  const float inve2 = 1.4426950408889634f/eps;   // log2(e)/eps

  const int kR = 8*w + l7;          // Layout-R row / Layout-C col
  const float lmu2R = LMU2[b*128+kR];
  const float lnu2C = LNU2[b*128+kR];
  const int n0 = 16*at + 4*lg;      // fragment n base

  f32x4 lkR[4], lkC[4];
  float luR = 0.f, lvC = 0.f;

  for (int outer=0; outer<5; outer++){
    // A) stage Sr hi/lo planes -> bufS
    #pragma unroll
    for (int i=0;i<4;i++)
      gload_lds16(SrHLb + i*16384 + tid*16, bufS + i*16384 + tid*16);

    // B) T planes -> bufT, av/bv
    {
      f32x4 avp = {0.f,0.f,0.f,0.f};
      float bvp = 0.f;
      #pragma unroll
      for (int jj=0;jj<4;jj++){
        f32x4 TR, TC;
        if (outer==0){
          const f32x4 nu4 = *(const f32x4*)(NUb + 16*p8 + 4*jj);
          const f32x4 mu4 = *(const f32x4*)(MUb + 16*p8 + 4*jj);
          const float muR = MUb[kR], nuC = NUb[kR];
          TR = muR*nu4; TC = mu4*nuC;
        } else {
          const f32x4 lv4 = *(const f32x4*)&lvs[16*p8 + 4*jj];
          const f32x4 lu4 = *(const f32x4*)&lus[16*p8 + 4*jj];
          #pragma unroll
          for (int e=0;e<4;e++){
            TR[e] = exp2f(lkR[jj][e] + luR + lv4[e]);
            TC[e] = exp2f(lkC[jj][e] + lu4[e] + lvC);
          }
        }
        u16x4 hi4, lo4;
        #pragma unroll
        for (int e=0;e<4;e++){
          u16 h = f2b(TR[e]); hi4[e] = h;
          lo4[e] = f2b(TR[e] - b2f(h));
        }
        const int sa = kR*256 + ((((2*p8+(jj>>1))^(kR&15)))<<4) + ((jj&1)<<3);
        *(u16x4*)(bufT + sa) = hi4;
        *(u16x4*)(bufT + 32768 + sa) = lo4;
        avp += TR;
        bvp += TC[0]+TC[1]+TC[2]+TC[3];
      }
      float av = avp[0]+avp[1]+avp[2]+avp[3];
      av += __shfl_xor(av,8); av += __shfl_xor(av,16); av += __shfl_xor(av,32);
      bvp += __shfl_xor(bvp,8); bvp += __shfl_xor(bvp,16); bvp += __shfl_xor(bvp,32);
      if (p8==0){ avs[kR] = av; bvs[kR] = bvp; }
    }
    __syncthreads();   // C

    // D) C-frag loads (early issue) + t1/t2
    f32x4 Cf[4];
    #pragma unroll
    for (int j=0;j<4;j++)
      Cf[j] = *(const f32x4*)(Cb + (size_t)(16*(4*par+j)+l15)*128 + n0);
    {
      const int k = tid>>3, sub = tid&7;
      const float* r1 = Sq2b + k*128 + 16*sub;
      const float* r2p = Sr2b + k*128 + 16*sub;
      f32x4 a1 = {0.f,0.f,0.f,0.f}, a2 = {0.f,0.f,0.f,0.f};
      #pragma unroll
      for (int i=0;i<4;i++){
        a1 += (*(const f32x4*)(r1+4*i)) * (*(const f32x4*)(avs+16*sub+4*i));
        a2 += (*(const f32x4*)(r2p+4*i)) * (*(const f32x4*)(bvs+16*sub+4*i));
      }
      float s1 = a1[0]+a1[1]+a1[2]+a1[3];
      float s2 = a2[0]+a2[1]+a2[2]+a2[3];
      s1 += __shfl_xor(s1,1); s1 += __shfl_xor(s1,2); s1 += __shfl_xor(s1,4);
      s2 += __shfl_xor(s2,1); s2 += __shfl_xor(s2,2); s2 += __shfl_xor(s2,4);
      if (sub==0){ t1s[k]=s1; t2s[k]=s2; }
    }
    // phase A: TSr = T @ Sr
    f32x4 acc1[4] = {};
    #pragma unroll
    for (int qt=0;qt<4;qt++){
      const int aoff = (16*at+l15)*256 + (((4*qt+lg)^l15)<<4);
      const bf16x8 ahi = *(const bf16x8*)(bufT + aoff);
      const bf16x8 alo = *(const bf16x8*)(bufT + 32768 + aoff);
      #pragma unroll
      for (int j=0;j<4;j++){
        const int boff = (16*(4*par+j)+l15)*256 + (((4*qt+lg)^l15)<<4);
        const bf16x8 bhi = *(const bf16x8*)(bufS + boff);
        const bf16x8 blo = *(const bf16x8*)(bufS + 32768 + boff);
        acc1[j] = __builtin_amdgcn_mfma_f32_16x16x32_bf16(ahi, bhi, acc1[j], 0,0,0);
        acc1[j] = __builtin_amdgcn_mfma_f32_16x16x32_bf16(ahi, blo, acc1[j], 0,0,0);
        acc1[j] = __builtin_amdgcn_mfma_f32_16x16x32_bf16(alo, bhi, acc1[j], 0,0,0);
      }
    }
    __syncthreads();   // E

    // F) stage Sq -> bufS ; write TSr^T planes -> bufT
    #pragma unroll
    for (int i=0;i<4;i++)
      gload_lds16(SqHLb + i*16384 + tid*16, bufS + i*16384 + tid*16);
    #pragma unroll
    for (int j=0;j<4;j++){
      u16x4 hi4, lo4;
      #pragma unroll
      for (int r=0;r<4;r++){
        u16 h = f2b(acc1[j][r]); hi4[r] = h;
        lo4[r] = f2b(acc1[j][r] - b2f(h));
      }
      const int sa = (16*(4*par+j)+l15)*256 + ((((2*at+(lg>>1))^l15))<<4) + ((lg&1)<<3);
      *(u16x4*)(bufT + sa) = hi4;
      *(u16x4*)(bufT + 32768 + sa) = lo4;
    }
    __syncthreads();   // G

    // H) phase B: G^T = TSr^T @ Sq ; lk in fragment layout
    f32x4 acc2[4] = {};
    #pragma unroll
    for (int qt=0;qt<4;qt++){
      const int aoff = (16*at+l15)*256 + (((4*qt+lg)^l15)<<4);
      const bf16x8 ahi = *(const bf16x8*)(bufT + aoff);
      const bf16x8 alo = *(const bf16x8*)(bufT + 32768 + aoff);
      #pragma unroll
      for (int j=0;j<4;j++){
        const int boff = (16*(4*par+j)+l15)*256 + (((4*qt+lg)^l15)<<4);
        const bf16x8 bhi = *(const bf16x8*)(bufS + boff);
        const bf16x8 blo = *(const bf16x8*)(bufS + 32768 + boff);
        acc2[j] = __builtin_amdgcn_mfma_f32_16x16x32_bf16(ahi, bhi, acc2[j], 0,0,0);
        acc2[j] = __builtin_amdgcn_mfma_f32_16x16x32_bf16(ahi, blo, acc2[j], 0,0,0);
        acc2[j] = __builtin_amdgcn_mfma_f32_16x16x32_bf16(alo, bhi, acc2[j], 0,0,0);
      }
    }
    f32x4 lkf[4];
    {
      const f32x4 t24 = *(const f32x4*)&t2s[n0];
      #pragma unroll
      for (int j=0;j<4;j++){
        const float t1v = t1s[16*(4*par+j)+l15];
        lkf[j] = -inve2*(0.5f*Cf[j] + 0.5f*(t1v + t24 - 2.0f*acc2[j]));
      }
    }
    __syncthreads();   // I

    // J) bounce: row-major f32 plane -> bufT, col-major -> bufS
    #pragma unroll
    for (int j=0;j<4;j++){
      const int kj = 16*(4*par+j)+l15;
      *(f32x4*)(bufT + kj*512 + (((4*at+lg)^(kj&31))<<4)) = lkf[j];
      #pragma unroll
      for (int r=0;r<4;r++){
        const int n = n0 + r;
        *(float*)(bufS + n*512 + ((((16*par+4*j+(l15>>2))^(n&31)))<<4) + ((l15&3)<<2))
          = lkf[j][r];
      }
    }
    __syncthreads();   // K
    #pragma unroll
    for (int jj=0;jj<4;jj++){
      lkR[jj] = *(const f32x4*)(bufT + kR*512 + (((4*p8+jj)^(kR&31))<<4));
      lkC[jj] = *(const f32x4*)(bufS + kR*512 + (((4*p8+jj)^(kR&31))<<4));
    }

    // M) Sinkhorn: 10 iters, base-2
    for (int it=0; it<10; it++){
      f32x4 y[4];
      #pragma unroll
      for (int jj=0;jj<4;jj++){
        y[jj] = lkR[jj];
        if (it) y[jj] += *(const f32x4*)&lvs[16*p8+4*jj];
      }
      f32x4 m4 = vmax4(vmax4(y[0],y[1]), vmax4(y[2],y[3]));
      float mx = fmaxf(fmaxf(m4[0],m4[1]), fmaxf(m4[2],m4[3]));
      mx = fmaxf(mx,__shfl_xor(mx,8)); mx = fmaxf(mx,__shfl_xor(mx,16));
      mx = fmaxf(mx,__shfl_xor(mx,32));
      f32x4 s4 = {0.f,0.f,0.f,0.f};
      #pragma unroll
      for (int jj=0;jj<4;jj++){
        #pragma unroll
        for (int e=0;e<4;e++) s4[e] += exp2f(y[jj][e]-mx);
      }
      float s = s4[0]+s4[1]+s4[2]+s4[3];
      s += __shfl_xor(s,8); s += __shfl_xor(s,16); s += __shfl_xor(s,32);
      luR = rho*(lmu2R - (mx + __log2f(s)));
      if (p8==0) lus[kR] = luR;
      __syncthreads();
      #pragma unroll
      for (int jj=0;jj<4;jj++)
        y[jj] = lkC[jj] + *(const f32x4*)&lus[16*p8+4*jj];
      m4 = vmax4(vmax4(y[0],y[1]), vmax4(y[2],y[3]));
      mx = fmaxf(fmaxf(m4[0],m4[1]), fmaxf(m4[2],m4[3]));
      mx = fmaxf(mx,__shfl_xor(mx,8)); mx = fmaxf(mx,__shfl_xor(mx,16));
      mx = fmaxf(mx,__shfl_xor(mx,32));
      s4 = (f32x4){0.f,0.f,0.f,0.f};
      #pragma unroll
      for (int jj=0;jj<4;jj++){
        #pragma unroll
        for (int e=0;e<4;e++) s4[e] += exp2f(y[jj][e]-mx);
      }
      s = s4[0]+s4[1]+s4[2]+s4[3];
      s += __shfl_xor(s,8); s += __shfl_xor(s,16); s += __shfl_xor(s,32);
      lvC = rho*(lnu2C - (mx + __log2f(s)));
      if (p8==0) lvs[kR] = lvC;
      __syncthreads();
    }

    if (outer==4){
      float cp = 0.f;
      float* Tb = T_out + (size_t)b*16384;
      #pragma unroll
      for (int jj=0;jj<4;jj++){
        const f32x4 lv4 = *(const f32x4*)&lvs[16*p8+4*jj];
        f32x4 t;
        #pragma unroll
        for (int e=0;e<4;e++) t[e] = exp2f(lkR[jj][e] + luR + lv4[e]);
        *(f32x4*)(Tb + kR*128 + 16*p8 + 4*jj) = t;
        const f32x4 pr = t*lkR[jj];
        cp += pr[0]+pr[1]+pr[2]+pr[3];
      }
      cp *= -eps*0.6931471805599453f;   // ln2: cost = sum T * (-eps*ln2*lk2)
      #pragma unroll
      for (int off=1;off<64;off<<=1) cp += __shfl_xor(cp, off);
      if (lane==0) redc[w] = cp;
      __syncthreads();
      if (tid==0){
        float tot = 0.f;
        #pragma unroll
        for (int w2=0;w2<16;w2++) tot += redc[w2];
        cost_out[b] = tot;
        sim_out[b]  = 1.0f/(1.0f + __expf(tot));
      }
    }
  }
}

// ---------------------------------------------------------------------------
extern "C" void kernel_launch(void* const* d_in, const int* in_sizes, int n_in,
                              void* d_out, int out_size, void* d_ws, size_t ws_size,
                              hipStream_t stream){
  const float* sq      = (const float*)d_in[0];
  const float* sr      = (const float*)d_in[1];
  const float* mask_q  = (const float*)d_in[2];
  const float* mask_r  = (const float*)d_in[3];
  const float* cq      = (const float*)d_in[4];
  const float* cr      = (const float*)d_in[5];
  const float* W1      = (const float*)d_in[6];
  const float* b1      = (const float*)d_in[7];
  const float* W2      = (const float*)d_in[8];
  const float* b2      = (const float*)d_in[9];
  const float* log_eps = (const float*)d_in[10];

  float* out  = (float*)d_out;
  float* sim  = out;                 // [256]
  float* Tm   = out + 256;           // [256][128][128]
  float* Cm   = Tm + 4194304;        // [256][128][128]
  float* cost = Cm + 4194304;        // [256]

  char* ws = (char*)d_ws;
  size_t off = 0;
  auto alloc = [&](size_t bytes)->void*{ void* p = ws + off; off += (bytes+255)&~(size_t)255; return p; };
  u16*   P   = (u16*)  alloc(67108864);   // 64MB: P bf16; later loop planes
  u16*   CQB = (u16*)  alloc(33554432);
  u16*   CRB = (u16*)  alloc(33554432);
  u16*   W1S = (u16*)  alloc(524288);
  u16*   W2S = (u16*)  alloc(524288);
  float* NP  = (float*)alloc(262144);
  float* NCQ = (float*)alloc(131072);
  float* NCR = (float*)alloc(131072);
  float* LMU = (float*)alloc(131072);
  float* LNU = (float*)alloc(131072);
  float* MUA = (float*)alloc(131072);
  float* NUA = (float*)alloc(131072);
  (void)ws_size; (void)in_sizes; (void)n_in; (void)out_size;

  // After pdist<0> consumes P, its region is reused for the loop planes:
  float* SQ2  = (float*)((char*)P);
  float* SR2  = (float*)((char*)P + 16777216);
  char*  SQHL = (char*)P + 33554432;
  char*  SRHL = (char*)P + 50331648;

  prepw_k<<<1024,256,0,stream>>>(W1, W1S);
  prepw_k<<<1024,256,0,stream>>>(W2, W2S);
  cvt_k<<<8192,256,0,stream>>>(cq, CQB, NCQ, 32768);
  cvt_k<<<8192,256,0,stream>>>(cr, CRB, NCR, 32768);
  mlp_k<<<1024,512,0,stream>>>(sq, sr, W1S, W2S, b1, b2, P, NP);
  pdist_k<0><<<256,256,0,stream>>>(P, P + (size_t)32768*512, NP, NP + 32768,
                                   Cm, nullptr, nullptr);
  pdist_k<1><<<256,256,0,stream>>>(CQB, CQB, NCQ, NCQ, nullptr, SQ2, SQHL);
  pdist_k<1><<<256,256,0,stream>>>(CRB, CRB, NCR, NCR, nullptr, SR2, SRHL);
  prep_k<<<256,128,0,stream>>>(mask_q, mask_r, LMU, LNU, MUA, NUA);
  fgw_loop_k<<<256,1024,0,stream>>>(SQHL, SRHL, SQ2, SR2, Cm, MUA, NUA, LMU, LNU,
                                    log_eps, Tm, cost, sim);
}

// Round 6
// 484.271 us; speedup vs baseline: 1.1173x; 1.1173x over previous
//
#include <hip/hip_runtime.h>
#include <math.h>

typedef unsigned short u16;
typedef __attribute__((ext_vector_type(4))) float f32x4;
typedef __attribute__((ext_vector_type(8))) short bf16x8;
typedef __attribute__((ext_vector_type(4))) unsigned short u16x4;
typedef __attribute__((ext_vector_type(8))) unsigned short u16x8;

#define DEVI static __device__ __forceinline__

DEVI float b2f(u16 u){ union{float f; unsigned i;} v; v.i = ((unsigned)u)<<16; return v.f; }
DEVI u16 f2b(float f){ union{float f; unsigned i;} v; v.f=f;
  unsigned r = v.i + 0x7fffu + ((v.i>>16)&1u); return (u16)(r>>16); }

DEVI void gload_lds16(const void* g, void* l){
  __builtin_amdgcn_global_load_lds((const __attribute__((address_space(1))) void*)g,
                                   (__attribute__((address_space(3))) void*)l, 16, 0, 0);
}

DEVI f32x4 vmax4(f32x4 a, f32x4 b){
  f32x4 r; r[0]=fmaxf(a[0],b[0]); r[1]=fmaxf(a[1],b[1]);
  r[2]=fmaxf(a[2],b[2]); r[3]=fmaxf(a[3],b[3]); return r;
}

// ---------------------------------------------------------------------------
// W (512x512 f32, row-major [k][c]) -> Wt bf16 [c][k] (plain layout)
__global__ void prepw_k(const float* __restrict__ W, u16* __restrict__ Wt){
  int id = blockIdx.x*256 + threadIdx.x;
  int k = id>>9, c = id&511;
  Wt[c*512 + k] = f2b(W[id]);
}

// f32 [nrows][512] -> linear bf16 (+ optional row norms of the bf16 values)
__global__ void cvt_k(const float* __restrict__ src, u16* __restrict__ dst,
                      float* __restrict__ norms, int nrows){
  int gw = (int)((blockIdx.x*blockDim.x + threadIdx.x)>>6);
  int lane = threadIdx.x & 63;
  if (gw >= nrows) return;
  const float* s = src + (size_t)gw*512;
  u16* d = dst + (size_t)gw*512;
  float acc = 0.f;
  #pragma unroll
  for (int q=0;q<2;q++){
    f32x4 v = *(const f32x4*)(s + q*256 + lane*4);
    u16x4 u;
    #pragma unroll
    for (int e=0;e<4;e++){
      u16 b = f2b(v[e]); u[e] = b;
      float fv = b2f(b); acc += fv*fv;
    }
    *(u16x4*)(d + q*256 + lane*4) = u;
  }
  if (norms != nullptr){
    #pragma unroll
    for (int off=1;off<64;off<<=1) acc += __shfl_xor(acc, off);
    if (lane==0) norms[gw] = acc;
  }
}

// ---------------------------------------------------------------------------
// OUT[r][c] = act(sum_k X[r][k]*W[k][c] + bias[c]); X bf16 [R][512], Wt [c][k].
// NORM: accumulate row norms of bf16(OUT) into NP via atomicAdd (NP pre-zeroed).
template<int ACT, int NORM>
__global__ __launch_bounds__(256) void gemm_k(const u16* __restrict__ X,
    const u16* __restrict__ Wt, const float* __restrict__ bias, u16* __restrict__ OUT,
    float* __restrict__ NP){
  __shared__ __align__(16) u16 sA[128*64];
  __shared__ __align__(16) u16 sB[128*64];
  const int tid = threadIdx.x, wave = tid>>6, lane = tid&63;
  const int bid = (blockIdx.x&7)*256 + (blockIdx.x>>3);
  const int rblk = bid>>2, cb = (bid&3)<<7;
  const u16* Xb = X + (size_t)rblk*(128*512);
  const u16* Wb = Wt + (size_t)cb*512;
  const int lrow = lane&15, lg = lane>>4, wr = wave>>1, wc = wave&1;
  f32x4 acc[4][4] = {};
  for (int s=0;s<8;s++){
    const int k0 = s<<6;
    #pragma unroll
    for (int q=0;q<4;q++){
      const int i = (wave<<2)+q;
      const int row = (i<<3) + (lane>>3);
      const int cd = (lane&7) ^ (row&7);
      gload_lds16(Xb + row*512 + k0 + (cd<<3), sA + i*512);
      gload_lds16(Wb + row*512 + k0 + (cd<<3), sB + i*512);
    }
    __syncthreads();
    #pragma unroll
    for (int kh=0;kh<2;kh++){
      bf16x8 a_[4], b_[4];
      #pragma unroll
      for (int i=0;i<4;i++){
        const int ra = (wr<<6)+(i<<4)+lrow;
        a_[i] = *(const bf16x8*)(sA + ra*64 + ((((kh<<2)+lg)^(ra&7))<<3));
        const int rb = (wc<<6)+(i<<4)+lrow;
        b_[i] = *(const bf16x8*)(sB + rb*64 + ((((kh<<2)+lg)^(rb&7))<<3));
      }
      #pragma unroll
      for (int i=0;i<4;i++)
        #pragma unroll
        for (int j=0;j<4;j++)
          acc[i][j] = __builtin_amdgcn_mfma_f32_16x16x32_bf16(a_[i], b_[j], acc[i][j], 0,0,0);
    }
    __syncthreads();
  }
  float nacc[4][4];
  if (NORM){
    #pragma unroll
    for (int i=0;i<4;i++)
      #pragma unroll
      for (int r=0;r<4;r++) nacc[i][r]=0.f;
  }
  #pragma unroll
  for (int j=0;j<4;j++){
    const int col = cb + (wc<<6) + (j<<4) + lrow;
    const float bv = bias[col];
    #pragma unroll
    for (int i=0;i<4;i++){
      const int row0 = (rblk<<7) + (wr<<6) + (i<<4) + (lg<<2);
      #pragma unroll
      for (int r=0;r<4;r++){
        float v = acc[i][j][r] + bv;
        if (ACT) v = fmaxf(v, 0.f);
        u16 pb = f2b(v);
        OUT[(size_t)(row0+r)*512 + col] = pb;
        if (NORM){ float fv = b2f(pb); nacc[i][r] += fv*fv; }
      }
    }
  }
  if (NORM){
    #pragma unroll
    for (int i=0;i<4;i++)
      #pragma unroll
      for (int r=0;r<4;r++){
        float v = nacc[i][r];
        v += __shfl_xor(v,1); v += __shfl_xor(v,2);
        v += __shfl_xor(v,4); v += __shfl_xor(v,8);
        if (lrow==0)
          atomicAdd(NP + (rblk<<7) + (wr<<6) + (i<<4) + (lg<<2) + r, v);
      }
  }
}

// pdist: MODE 0 -> OUT f32 [b][k][m]. MODE 1 -> SHL hi/lo bf16 planes,
// transposed + XOR-granule-swizzled (key = plane-row & 15).
template<int MODE>
__global__ __launch_bounds__(256) void pdist_k(const u16* __restrict__ Xa,
    const u16* __restrict__ Xb2, const float* __restrict__ na, const float* __restrict__ nb,
    float* __restrict__ OUT, char* __restrict__ SHL){
  __shared__ __align__(16) u16 sA[128*64];
  __shared__ __align__(16) u16 sB[128*64];
  const int tid = threadIdx.x, wave = tid>>6, lane = tid&63;
  const int b = blockIdx.x;
  const u16* Ab = Xa + (size_t)b*(128*512);
  const u16* Bb = Xb2 + (size_t)b*(128*512);
  const int lrow = lane&15, lg = lane>>4, wr = wave>>1, wc = wave&1;
  f32x4 acc[4][4] = {};
  for (int s=0;s<8;s++){
    const int k0 = s<<6;
    #pragma unroll
    for (int q=0;q<4;q++){
      const int i = (wave<<2)+q;
      const int row = (i<<3) + (lane>>3);
      const int cd = (lane&7) ^ (row&7);
      gload_lds16(Ab + row*512 + k0 + (cd<<3), sA + i*512);
      gload_lds16(Bb + row*512 + k0 + (cd<<3), sB + i*512);
    }
    __syncthreads();
    #pragma unroll
    for (int kh=0;kh<2;kh++){
      bf16x8 a_[4], b_[4];
      #pragma unroll
      for (int i=0;i<4;i++){
        const int ra = (wr<<6)+(i<<4)+lrow;
        a_[i] = *(const bf16x8*)(sA + ra*64 + ((((kh<<2)+lg)^(ra&7))<<3));
        const int rb = (wc<<6)+(i<<4)+lrow;
        b_[i] = *(const bf16x8*)(sB + rb*64 + ((((kh<<2)+lg)^(rb&7))<<3));
      }
      #pragma unroll
      for (int i=0;i<4;i++)
        #pragma unroll
        for (int j=0;j<4;j++)
          acc[i][j] = __builtin_amdgcn_mfma_f32_16x16x32_bf16(a_[i], b_[j], acc[i][j], 0,0,0);
    }
    __syncthreads();
  }
  #pragma unroll
  for (int j=0;j<4;j++){
    const int col = (wc<<6)+(j<<4)+lrow;
    const float nbv = nb[b*128+col];
    #pragma unroll
    for (int i=0;i<4;i++){
      const int row0 = (wr<<6)+(i<<4)+(lg<<2);
      float sv[4];
      #pragma unroll
      for (int r=0;r<4;r++){
        float n2 = na[b*128+row0+r] + nbv - 2.0f*acc[i][j][r];
        sv[r] = sqrtf(fmaxf(n2, 1e-6f));
      }
      if (MODE==0){
        #pragma unroll
        for (int r=0;r<4;r++)
          OUT[(size_t)b*16384 + (size_t)(row0+r)*128 + col] = sv[r];
      } else {
        u16x4 hi4, lo4;
        #pragma unroll
        for (int r=0;r<4;r++){
          u16 h = f2b(sv[r]); hi4[r] = h;
          lo4[r] = f2b(sv[r] - b2f(h));
        }
        const int sa = col*256 + ((((row0>>3)^col)&15)<<4) + ((row0&7)<<1);
        char* base = SHL + (size_t)b*65536;
        *(u16x4*)(base + sa) = hi4;
        *(u16x4*)(base + 32768 + sa) = lo4;
      }
    }
  }
}

// ---------------------------------------------------------------------------
// mu/nu + base-2 logs. 256 blocks x 128 threads.
__global__ void prep_k(const float* __restrict__ mask_q, const float* __restrict__ mask_r,
                       float* __restrict__ lmu2, float* __restrict__ lnu2,
                       float* __restrict__ mu, float* __restrict__ nu){
  int b = blockIdx.x, t = threadIdx.x;
  __shared__ float red[4];
  float mq = mask_q[b*128+t], mr = mask_r[b*128+t];
  float s1 = mq, s2 = mr;
  #pragma unroll
  for (int off=1;off<64;off<<=1){ s1 += __shfl_xor(s1,off); s2 += __shfl_xor(s2,off); }
  if ((t&63)==0){ red[t>>6] = s1; red[2+(t>>6)] = s2; }
  __syncthreads();
  float sumq = red[0]+red[1], sumr = red[2]+red[3];
  float muv = mq/(sumq+1e-8f), nuv = mr/(sumr+1e-8f);
  lmu2[b*128+t] = __log2f(fmaxf(muv,1e-8f));
  lnu2[b*128+t] = __log2f(fmaxf(nuv,1e-8f));
  mu[b*128+t] = muv;
  nu[b*128+t] = nuv;
}

// ---------------------------------------------------------------------------
// 5-iter FGW loop, 512 threads/block (8 waves), base-2 domain.
// C resident in registers across outers; t1/t2 from LDS hi/lo planes.
// Sinkhorn dual layouts: Layout-R thread owns row kR=16w+l15, cols 16q+4lg+e;
// Layout-C owns col nC=kR, rows 16q+4lg+e.
__global__ __launch_bounds__(512,1) void fgw_loop_k(
    const char* __restrict__ SQHL, const char* __restrict__ SRHL,
    const float* __restrict__ C_g,
    const float* __restrict__ MU, const float* __restrict__ NU,
    const float* __restrict__ LMU2, const float* __restrict__ LNU2,
    const float* __restrict__ log_eps,
    float* __restrict__ T_out, float* __restrict__ cost_out, float* __restrict__ sim_out)
{
  __shared__ __align__(16) char bufT[65536];   // T planes / TSr^T planes / lk row-major
  __shared__ __align__(16) char bufS[65536];   // Sr planes / Sq planes / lk col-major
  __shared__ __align__(16) float avs[128], bvs[128], t1s[128], t2s[128];
  __shared__ __align__(16) float lus[128], lvs[128];
  __shared__ float redc[8];

  const int b = blockIdx.x, tid = threadIdx.x;
  const int w = tid>>6, lane = tid&63, l15 = lane&15, lg = lane>>4;
  const char* SqHLb = SQHL + (size_t)b*65536;
  const char* SrHLb = SRHL + (size_t)b*65536;
  const float* Cb   = C_g + (size_t)b*16384;
  const float* MUb  = MU + b*128;
  const float* NUb  = NU + b*128;

  float eps = __expf(log_eps[0]); eps = fminf(fmaxf(eps,0.01f),0.5f);
  const float rho = 0.1f/(0.1f+eps);
  const float hscale = 0.5f*1.4426950408889634f/eps;   // 0.5*log2(e)/eps

  const int kR = 16*w + l15;       // Layout-R row / Layout-C col
  const int n0 = 16*w + 4*lg;      // fragment n base
  const float lmu2R = LMU2[b*128+kR];
  const float lnu2C = LNU2[b*128+kR];

  const int rowA256 = (16*w + l15)*256;
  const int glo2 = lg ^ (l15 & 3);
  const int ghi2 = l15 & 12;
  const int wtail = l15*256 + ((((2*w + (lg>>1)) ^ l15)&15)<<4) + ((lg&1)<<3);

  // resident C fragments, pre-scaled: Cf2 = -hscale * C[16kt+l15][n0..n0+3]
  f32x4 Cf2[8];
  #pragma unroll
  for (int kt=0;kt<8;kt++)
    Cf2[kt] = -hscale * (*(const f32x4*)(Cb + (size_t)(16*kt+l15)*128 + n0));

  f32x4 lkR[8], lkC[8];
  float luR = 0.f, lvC = 0.f;

  for (int outer=0; outer<5; outer++){
    // ---- P0: stage Sr; T planes + avs/bvs
    #pragma unroll
    for (int r2=0;r2<8;r2++)
      gload_lds16(SrHLb + r2*8192 + tid*16, bufS + r2*8192 + tid*16);
    {
      f32x4 avp = {0.f,0.f,0.f,0.f};
      float bvp = 0.f;
      #pragma unroll
      for (int q=0;q<8;q++){
        f32x4 TR, TC;
        if (outer==0){
          const f32x4 nu4 = *(const f32x4*)(NUb + 16*q + 4*lg);
          const f32x4 mu4 = *(const f32x4*)(MUb + 16*q + 4*lg);
          const float muR = MUb[kR], nuC = NUb[kR];
          TR = muR*nu4; TC = mu4*nuC;
        } else {
          const f32x4 lv4 = *(const f32x4*)&lvs[16*q + 4*lg];
          const f32x4 lu4 = *(const f32x4*)&lus[16*q + 4*lg];
          #pragma unroll
          for (int e=0;e<4;e++){
            TR[e] = exp2f(lkR[q][e] + luR + lv4[e]);
            TC[e] = exp2f(lkC[q][e] + lu4[e] + lvC);
          }
        }
        u16x4 hi4, lo4;
        #pragma unroll
        for (int e=0;e<4;e++){
          u16 h = f2b(TR[e]); hi4[e] = h;
          lo4[e] = f2b(TR[e] - b2f(h));
        }
        const int sa = kR*256 + ((((2*q+(lg>>1)) ^ l15)&15)<<4) + ((lg&1)<<3);
        *(u16x4*)(bufT + sa) = hi4;
        *(u16x4*)(bufT + 32768 + sa) = lo4;
        avp += TR;
        bvp += TC[0]+TC[1]+TC[2]+TC[3];
      }
      float av = avp[0]+avp[1]+avp[2]+avp[3];
      av += __shfl_xor(av,16); av += __shfl_xor(av,32);
      bvp += __shfl_xor(bvp,16); bvp += __shfl_xor(bvp,32);
      if (lg==0){ avs[kR] = av; bvs[kR] = bvp; }
    }
    __syncthreads();   // C: Sr staged, T planes, avs/bvs

    // ---- P1: t2 from Sr planes (bufS) + bvs; phase A MFMA
    {
      const int p = tid>>2, sub = tid&3;     // row p, m in [32sub,32sub+32)
      float s2 = 0.f;
      #pragma unroll
      for (int gg=0; gg<4; gg++){
        const int g = 4*sub+gg;
        const int off = p*256 + (((g ^ (p&15))&15)<<4);
        const u16x8 h8 = *(const u16x8*)(bufS + off);
        const u16x8 l8 = *(const u16x8*)(bufS + 32768 + off);
        const f32x4 bva = *(const f32x4*)&bvs[8*g];
        const f32x4 bvb = *(const f32x4*)&bvs[8*g+4];
        #pragma unroll
        for (int e=0;e<4;e++){
          float x = b2f(h8[e]) + b2f(l8[e]);
          s2 = fmaf(bva[e], x*x, s2);
          float y2 = b2f(h8[4+e]) + b2f(l8[4+e]);
          s2 = fmaf(bvb[e], y2*y2, s2);
        }
      }
      s2 += __shfl_xor(s2,1); s2 += __shfl_xor(s2,2);
      if (sub==0) t2s[p] = s2;
    }
    f32x4 acc1[8] = {};
    #pragma unroll
    for (int qt=0;qt<4;qt++){
      const int colOff = (((4*qt) ^ ghi2) | glo2) << 4;
      const bf16x8 ahi = *(const bf16x8*)(bufT + rowA256 + colOff);
      const bf16x8 alo = *(const bf16x8*)(bufT + 32768 + rowA256 + colOff);
      const int bbase = l15*256 + colOff;
      #pragma unroll
      for (int nt=0;nt<8;nt++){
        const bf16x8 bhi = *(const bf16x8*)(bufS + nt*4096 + bbase);
        const bf16x8 blo = *(const bf16x8*)(bufS + 32768 + nt*4096 + bbase);
        acc1[nt] = __builtin_amdgcn_mfma_f32_16x16x32_bf16(ahi, bhi, acc1[nt], 0,0,0);
        acc1[nt] = __builtin_amdgcn_mfma_f32_16x16x32_bf16(ahi, blo, acc1[nt], 0,0,0);
        acc1[nt] = __builtin_amdgcn_mfma_f32_16x16x32_bf16(alo, bhi, acc1[nt], 0,0,0);
      }
    }
    __syncthreads();   // E: phase-A reads done, t2s written

    // ---- P2: stage Sq; write TSr^T planes
    #pragma unroll
    for (int r2=0;r2<8;r2++)
      gload_lds16(SqHLb + r2*8192 + tid*16, bufS + r2*8192 + tid*16);
    #pragma unroll
    for (int nt=0;nt<8;nt++){
      u16x4 hi4, lo4;
      #pragma unroll
      for (int r=0;r<4;r++){
        u16 h = f2b(acc1[nt][r]); hi4[r] = h;
        lo4[r] = f2b(acc1[nt][r] - b2f(h));
      }
      const int sa = nt*4096 + wtail;
      *(u16x4*)(bufT + sa) = hi4;
      *(u16x4*)(bufT + 32768 + sa) = lo4;
    }
    __syncthreads();   // G: Sq staged + TSr^T planes

    // ---- P3: t1 from Sq planes (bufS) + avs; phase B MFMA
    {
      const int p = tid>>2, sub = tid&3;
      float s1 = 0.f;
      #pragma unroll
      for (int gg=0; gg<4; gg++){
        const int g = 4*sub+gg;
        const int off = p*256 + (((g ^ (p&15))&15)<<4);
        const u16x8 h8 = *(const u16x8*)(bufS + off);
        const u16x8 l8 = *(const u16x8*)(bufS + 32768 + off);
        const f32x4 ava = *(const f32x4*)&avs[8*g];
        const f32x4 avb = *(const f32x4*)&avs[8*g+4];
        #pragma unroll
        for (int e=0;e<4;e++){
          float x = b2f(h8[e]) + b2f(l8[e]);
          s1 = fmaf(ava[e], x*x, s1);
          float y2 = b2f(h8[4+e]) + b2f(l8[4+e]);
          s1 = fmaf(avb[e], y2*y2, s1);
        }
      }
      s1 += __shfl_xor(s1,1); s1 += __shfl_xor(s1,2);
      if (sub==0) t1s[p] = s1;
    }
    f32x4 acc2[8] = {};
    #pragma unroll
    for (int qt=0;qt<4;qt++){
      const int colOff = (((4*qt) ^ ghi2) | glo2) << 4;
      const bf16x8 ahi = *(const bf16x8*)(bufT + rowA256 + colOff);
      const bf16x8 alo = *(const bf16x8*)(bufT + 32768 + rowA256 + colOff);
      const int bbase = l15*256 + colOff;
      #pragma unroll
      for (int kt=0;kt<8;kt++){
        const bf16x8 bhi = *(const bf16x8*)(bufS + kt*4096 + bbase);
        const bf16x8 blo = *(const bf16x8*)(bufS + 32768 + kt*4096 + bbase);
        acc2[kt] = __builtin_amdgcn_mfma_f32_16x16x32_bf16(ahi, bhi, acc2[kt], 0,0,0);
        acc2[kt] = __builtin_amdgcn_mfma_f32_16x16x32_bf16(ahi, blo, acc2[kt], 0,0,0);
        acc2[kt] = __builtin_amdgcn_mfma_f32_16x16x32_bf16(alo, bhi, acc2[kt], 0,0,0);
      }
    }
    __syncthreads();   // I: phase-B reads done; t1s/t2s visible

    // ---- P4: lk build (regs) + bounce writes
    f32x4 lkf[8];
    {
      const f32x4 t24 = *(const f32x4*)&t2s[n0];
      #pragma unroll
      for (int kt=0;kt<8;kt++){
        const float t1v = t1s[16*kt+l15];
        lkf[kt] = Cf2[kt] + hscale*(2.0f*acc2[kt] - t1v - t24);
      }
    }
    #pragma unroll
    for (int kt=0;kt<8;kt++){
      const int row = 16*kt + l15;
      const int gp = ((4*w+lg) ^ (row&31)) & 31;
      *(f32x4*)(bufT + row*512 + gp*16) = lkf[kt];
      #pragma unroll
      for (int e=0;e<4;e++){
        const int n = n0 + e;
        const int gt = ((4*kt + (l15>>2)) ^ (n&31)) & 31;
        *(float*)(bufS + n*512 + gt*16 + (l15&3)*4) = lkf[kt][e];
      }
    }
    __syncthreads();   // K
    #pragma unroll
    for (int q=0;q<8;q++){
      const int g1 = ((4*q+lg) ^ (kR&31)) & 31;
      lkR[q] = *(const f32x4*)(bufT + kR*512 + g1*16);
      lkC[q] = *(const f32x4*)(bufS + kR*512 + g1*16);
    }

    // ---- Sinkhorn: 10 iterations, base-2
    for (int it=0; it<10; it++){
      f32x4 y[8];
      #pragma unroll
      for (int q=0;q<8;q++){
        y[q] = lkR[q];
        if (it) y[q] += *(const f32x4*)&lvs[16*q+4*lg];
      }
      f32x4 m4 = vmax4(vmax4(vmax4(y[0],y[1]),vmax4(y[2],y[3])),
                       vmax4(vmax4(y[4],y[5]),vmax4(y[6],y[7])));
      float mx = fmaxf(fmaxf(m4[0],m4[1]), fmaxf(m4[2],m4[3]));
      mx = fmaxf(mx,__shfl_xor(mx,16)); mx = fmaxf(mx,__shfl_xor(mx,32));
      f32x4 s4 = {0.f,0.f,0.f,0.f};
      #pragma unroll
      for (int q=0;q<8;q++){
        #pragma unroll
        for (int e=0;e<4;e++) s4[e] += exp2f(y[q][e]-mx);
      }
      float s = s4[0]+s4[1]+s4[2]+s4[3];
      s += __shfl_xor(s,16); s += __shfl_xor(s,32);
      luR = rho*(lmu2R - (mx + __log2f(s)));
      if (lg==0) lus[kR] = luR;
      __syncthreads();
      #pragma unroll
      for (int q=0;q<8;q++)
        y[q] = lkC[q] + *(const f32x4*)&lus[16*q+4*lg];
      m4 = vmax4(vmax4(vmax4(y[0],y[1]),vmax4(y[2],y[3])),
                 vmax4(vmax4(y[4],y[5]),vmax4(y[6],y[7])));
      mx = fmaxf(fmaxf(m4[0],m4[1]), fmaxf(m4[2],m4[3]));
      mx = fmaxf(mx,__shfl_xor(mx,16)); mx = fmaxf(mx,__shfl_xor(mx,32));
      s4 = (f32x4){0.f,0.f,0.f,0.f};
      #pragma unroll
      for (int q=0;q<8;q++){
        #pragma unroll
        for (int e=0;e<4;e++) s4[e] += exp2f(y[q][e]-mx);
      }
      s = s4[0]+s4[1]+s4[2]+s4[3];
      s += __shfl_xor(s,16); s += __shfl_xor(s,32);
      lvC = rho*(lnu2C - (mx + __log2f(s)));
      if (lg==0) lvs[kR] = lvC;
      __syncthreads();
    }

    if (outer==4){
      float cp = 0.f;
      float* Tb = T_out + (size_t)b*16384;
      #pragma unroll
      for (int q=0;q<8;q++){
        const f32x4 lv4 = *(const f32x4*)&lvs[16*q+4*lg];
        f32x4 t;
        #pragma unroll
        for (int e=0;e<4;e++) t[e] = exp2f(lkR[q][e] + luR + lv4[e]);
        *(f32x4*)(Tb + kR*128 + 16*q + 4*lg) = t;
        const f32x4 pr = t*lkR[q];
        cp += pr[0]+pr[1]+pr[2]+pr[3];
      }
      cp *= -eps*0.6931471805599453f;        // cost = sum T * (-eps*ln2*lk2)
      #pragma unroll
      for (int off=1;off<64;off<<=1) cp += __shfl_xor(cp, off);
      if (lane==0) redc[w] = cp;
      __syncthreads();
      if (tid==0){
        float tot = 0.f;
        #pragma unroll
        for (int w2=0;w2<8;w2++) tot += redc[w2];
        cost_out[b] = tot;
        sim_out[b]  = 1.0f/(1.0f + __expf(tot));
      }
    }
  }
}

// ---------------------------------------------------------------------------
extern "C" void kernel_launch(void* const* d_in, const int* in_sizes, int n_in,
                              void* d_out, int out_size, void* d_ws, size_t ws_size,
                              hipStream_t stream){
  const float* sq      = (const float*)d_in[0];
  const float* sr      = (const float*)d_in[1];
  const float* mask_q  = (const float*)d_in[2];
  const float* mask_r  = (const float*)d_in[3];
  const float* cq      = (const float*)d_in[4];
  const float* cr      = (const float*)d_in[5];
  const float* W1      = (const float*)d_in[6];
  const float* b1      = (const float*)d_in[7];
  const float* W2      = (const float*)d_in[8];
  const float* b2      = (const float*)d_in[9];
  const float* log_eps = (const float*)d_in[10];

  float* out  = (float*)d_out;
  float* sim  = out;                 // [256]
  float* Tm   = out + 256;           // [256][128][128]
  float* Cm   = Tm + 4194304;        // [256][128][128]
  float* cost = Cm + 4194304;        // [256]

  char* ws = (char*)d_ws;
  size_t off = 0;
  auto alloc = [&](size_t bytes)->void*{ void* p = ws + off; off += (bytes+255)&~(size_t)255; return p; };
  u16*   SQB = (u16*)  alloc(33554432);   // sq bf16; gemm2 writes P rows 0..32767 here
  u16*   SRB = (u16*)  alloc(33554432);   // sr bf16; P rows 32768..65535 (contiguous)
  u16*   HQ  = (u16*)  alloc(33554432);   // hidden; later cq bf16
  u16*   HR  = (u16*)  alloc(33554432);   // hidden; later cr bf16
  u16*   W1T = (u16*)  alloc(524288);
  u16*   W2T = (u16*)  alloc(524288);
  float* NP  = (float*)alloc(262144);     // row norms of P (65536), atomic-accumulated
  float* NCQ = (float*)alloc(131072);
  float* NCR = (float*)alloc(131072);
  float* LMU = (float*)alloc(131072);
  float* LNU = (float*)alloc(131072);
  float* MUA = (float*)alloc(131072);
  float* NUA = (float*)alloc(131072);
  (void)ws_size; (void)in_sizes; (void)n_in; (void)out_size;

  u16* PQ  = SQB;          // gemm2 output (65536 rows, spans SQB+SRB)
  u16* CQB = HQ;
  u16* CRB = HR;

  // After pdist<0> consumes P, its region is reused for the loop planes:
  char* SQHL = (char*)SQB;                 // 16MB bf16 hi/lo Sq planes
  char* SRHL = (char*)SQB + 16777216;      // 16MB bf16 hi/lo Sr planes

  prepw_k<<<1024,256,0,stream>>>(W1, W1T);
  prepw_k<<<1024,256,0,stream>>>(W2, W2T);
  cvt_k<<<8192,256,0,stream>>>(sq, SQB, nullptr, 32768);
  cvt_k<<<8192,256,0,stream>>>(sr, SRB, nullptr, 32768);
  gemm_k<1,0><<<2048,256,0,stream>>>(SQB, W1T, b1, HQ, nullptr);  // H = relu(X@W1+b1)
  hipMemsetAsync(NP, 0, 262144, stream);
  gemm_k<0,1><<<2048,256,0,stream>>>(HQ, W2T, b2, PQ, NP);        // P = H@W2+b2 (+norms)
  cvt_k<<<8192,256,0,stream>>>(cq, CQB, NCQ, 32768);
  cvt_k<<<8192,256,0,stream>>>(cr, CRB, NCR, 32768);
  pdist_k<0><<<256,256,0,stream>>>(PQ, PQ + (size_t)32768*512, NP, NP + 32768,
                                   Cm, nullptr);
  pdist_k<1><<<256,256,0,stream>>>(CQB, CQB, NCQ, NCQ, nullptr, SQHL);
  pdist_k<1><<<256,256,0,stream>>>(CRB, CRB, NCR, NCR, nullptr, SRHL);
  prep_k<<<256,128,0,stream>>>(mask_q, mask_r, LMU, LNU, MUA, NUA);
  fgw_loop_k<<<256,512,0,stream>>>(SQHL, SRHL, Cm, MUA, NUA, LMU, LNU,
                                   log_eps, Tm, cost, sim);
}

// Round 8
// 456.617 us; speedup vs baseline: 1.1849x; 1.0606x over previous
//
#include <hip/hip_runtime.h>
#include <math.h>

typedef unsigned short u16;
typedef __attribute__((ext_vector_type(4))) float f32x4;
typedef __attribute__((ext_vector_type(8))) short bf16x8;
typedef __attribute__((ext_vector_type(4))) unsigned short u16x4;
typedef __attribute__((ext_vector_type(8))) unsigned short u16x8;

#define DEVI static __device__ __forceinline__

DEVI float b2f(u16 u){ union{float f; unsigned i;} v; v.i = ((unsigned)u)<<16; return v.f; }
DEVI u16 f2b(float f){ union{float f; unsigned i;} v; v.f=f;
  unsigned r = v.i + 0x7fffu + ((v.i>>16)&1u); return (u16)(r>>16); }

DEVI void gload_lds16(const void* g, void* l){
  __builtin_amdgcn_global_load_lds((const __attribute__((address_space(1))) void*)g,
                                   (__attribute__((address_space(3))) void*)l, 16, 0, 0);
}

DEVI f32x4 vmax4(f32x4 a, f32x4 b){
  f32x4 r; r[0]=fmaxf(a[0],b[0]); r[1]=fmaxf(a[1],b[1]);
  r[2]=fmaxf(a[2],b[2]); r[3]=fmaxf(a[3],b[3]); return r;
}

// ---------------------------------------------------------------------------
// W (512x512 f32, row-major [k][c]) -> Wt bf16 [c][k] (plain layout)
__global__ void prepw_k(const float* __restrict__ W, u16* __restrict__ Wt){
  int id = blockIdx.x*256 + threadIdx.x;
  int k = id>>9, c = id&511;
  Wt[c*512 + k] = f2b(W[id]);
}

// ---------------------------------------------------------------------------
// OUT[r][c] = act(sum_k X[r][k]*W[k][c] + bias[c]); Wt bf16 [c][k].
// AF32: A-tile reg-staged from f32 sources (rows 0..32767 from Xf1, rest Xf2).
// NORM: accumulate row norms of bf16(OUT) into NP via atomicAdd (NP pre-zeroed).
template<int ACT, int NORM, int AF32>
__global__ __launch_bounds__(256) void gemm_k(const u16* __restrict__ X,
    const float* __restrict__ Xf1, const float* __restrict__ Xf2,
    const u16* __restrict__ Wt, const float* __restrict__ bias, u16* __restrict__ OUT,
    float* __restrict__ NP){
  __shared__ __align__(16) u16 sA[128*64];
  __shared__ __align__(16) u16 sB[128*64];
  const int tid = threadIdx.x, wave = tid>>6, lane = tid&63;
  const int bid = (blockIdx.x&7)*256 + (blockIdx.x>>3);
  const int rblk = bid>>2, cb = (bid&3)<<7;
  const u16* Xb = AF32 ? nullptr : (X + (size_t)rblk*(128*512));
  const float* Xbf = AF32 ? (rblk<256 ? Xf1 + (size_t)rblk*65536
                                      : Xf2 + (size_t)(rblk-256)*65536) : nullptr;
  const u16* Wb = Wt + (size_t)cb*512;
  const int lrow = lane&15, lg = lane>>4, wr = wave>>1, wc = wave&1;
  f32x4 acc[4][4] = {};
  for (int s=0;s<8;s++){
    const int k0 = s<<6;
    #pragma unroll
    for (int q=0;q<4;q++){
      const int i = (wave<<2)+q;
      const int row = (i<<3) + (lane>>3);
      const int cd = (lane&7) ^ (row&7);
      if (AF32){
        const float* src = Xbf + row*512 + k0 + (cd<<3);
        const f32x4 va = *(const f32x4*)src;
        const f32x4 vb = *(const f32x4*)(src+4);
        u16x8 t;
        #pragma unroll
        for (int e=0;e<4;e++){ t[e]=f2b(va[e]); t[4+e]=f2b(vb[e]); }
        *(u16x8*)((char*)sA + i*1024 + lane*16) = t;
      } else {
        gload_lds16(Xb + row*512 + k0 + (cd<<3), sA + i*512);
      }
      gload_lds16(Wb + row*512 + k0 + (cd<<3), sB + i*512);
    }
    __syncthreads();
    #pragma unroll
    for (int kh=0;kh<2;kh++){
      bf16x8 a_[4], b_[4];
      #pragma unroll
      for (int i=0;i<4;i++){
        const int ra = (wr<<6)+(i<<4)+lrow;
        a_[i] = *(const bf16x8*)(sA + ra*64 + ((((kh<<2)+lg)^(ra&7))<<3));
        const int rb = (wc<<6)+(i<<4)+lrow;
        b_[i] = *(const bf16x8*)(sB + rb*64 + ((((kh<<2)+lg)^(rb&7))<<3));
      }
      #pragma unroll
      for (int i=0;i<4;i++)
        #pragma unroll
        for (int j=0;j<4;j++)
          acc[i][j] = __builtin_amdgcn_mfma_f32_16x16x32_bf16(a_[i], b_[j], acc[i][j], 0,0,0);
    }
    __syncthreads();
  }
  float nacc[4][4];
  if (NORM){
    #pragma unroll
    for (int i=0;i<4;i++)
      #pragma unroll
      for (int r=0;r<4;r++) nacc[i][r]=0.f;
  }
  #pragma unroll
  for (int j=0;j<4;j++){
    const int col = cb + (wc<<6) + (j<<4) + lrow;
    const float bv = bias[col];
    #pragma unroll
    for (int i=0;i<4;i++){
      const int row0 = (rblk<<7) + (wr<<6) + (i<<4) + (lg<<2);
      #pragma unroll
      for (int r=0;r<4;r++){
        float v = acc[i][j][r] + bv;
        if (ACT) v = fmaxf(v, 0.f);
        u16 pb = f2b(v);
        OUT[(size_t)(row0+r)*512 + col] = pb;
        if (NORM){ float fv = b2f(pb); nacc[i][r] += fv*fv; }
      }
    }
  }
  if (NORM){
    #pragma unroll
    for (int i=0;i<4;i++)
      #pragma unroll
      for (int r=0;r<4;r++){
        float v = nacc[i][r];
        v += __shfl_xor(v,1); v += __shfl_xor(v,2);
        v += __shfl_xor(v,4); v += __shfl_xor(v,8);
        if (lrow==0)
          atomicAdd(NP + (rblk<<7) + (wr<<6) + (i<<4) + (lg<<2) + r, v);
      }
  }
}

// ---------------------------------------------------------------------------
// pdist0: C[b][k][m] = sqrt(max(na+nb-2*dot,1e-6)); bf16 inputs, ext. norms.
__global__ __launch_bounds__(256) void pdist0_k(const u16* __restrict__ Xa,
    const u16* __restrict__ Xb2, const float* __restrict__ na, const float* __restrict__ nb,
    float* __restrict__ OUT){
  __shared__ __align__(16) u16 sA[128*64];
  __shared__ __align__(16) u16 sB[128*64];
  const int tid = threadIdx.x, wave = tid>>6, lane = tid&63;
  const int b = blockIdx.x;
  const u16* Ab = Xa + (size_t)b*(128*512);
  const u16* Bb = Xb2 + (size_t)b*(128*512);
  const int lrow = lane&15, lg = lane>>4, wr = wave>>1, wc = wave&1;
  f32x4 acc[4][4] = {};
  for (int s=0;s<8;s++){
    const int k0 = s<<6;
    #pragma unroll
    for (int q=0;q<4;q++){
      const int i = (wave<<2)+q;
      const int row = (i<<3) + (lane>>3);
      const int cd = (lane&7) ^ (row&7);
      gload_lds16(Ab + row*512 + k0 + (cd<<3), sA + i*512);
      gload_lds16(Bb + row*512 + k0 + (cd<<3), sB + i*512);
    }
    __syncthreads();
    #pragma unroll
    for (int kh=0;kh<2;kh++){
      bf16x8 a_[4], b_[4];
      #pragma unroll
      for (int i=0;i<4;i++){
        const int ra = (wr<<6)+(i<<4)+lrow;
        a_[i] = *(const bf16x8*)(sA + ra*64 + ((((kh<<2)+lg)^(ra&7))<<3));
        const int rb = (wc<<6)+(i<<4)+lrow;
        b_[i] = *(const bf16x8*)(sB + rb*64 + ((((kh<<2)+lg)^(rb&7))<<3));
      }
      #pragma unroll
      for (int i=0;i<4;i++)
        #pragma unroll
        for (int j=0;j<4;j++)
          acc[i][j] = __builtin_amdgcn_mfma_f32_16x16x32_bf16(a_[i], b_[j], acc[i][j], 0,0,0);
    }
    __syncthreads();
  }
  #pragma unroll
  for (int j=0;j<4;j++){
    const int col = (wc<<6)+(j<<4)+lrow;
    const float nbv = nb[b*128+col];
    #pragma unroll
    for (int i=0;i<4;i++){
      const int row0 = (wr<<6)+(i<<4)+(lg<<2);
      #pragma unroll
      for (int r=0;r<4;r++){
        float n2 = na[b*128+row0+r] + nbv - 2.0f*acc[i][j][r];
        OUT[(size_t)b*16384 + (size_t)(row0+r)*128 + col] = sqrtf(fmaxf(n2, 1e-6f));
      }
    }
  }
}

// pdistS: symmetric self-distance from f32 source; reg-stage f32->bf16 into a
// single LDS buffer; row norms of the bf16 values computed during staging.
// Output: SHL hi/lo bf16 planes, transposed + XOR-granule-swizzled.
__global__ __launch_bounds__(256) void pdistS_k(const float* __restrict__ Sf,
    char* __restrict__ SHL){
  __shared__ __align__(16) u16 sA[128*64];
  __shared__ float nrm[128];
  const int tid = threadIdx.x, wave = tid>>6, lane = tid&63;
  const int b = blockIdx.x;
  const float* Sb = Sf + (size_t)b*65536;
  const int lrow = lane&15, lg = lane>>4, wr = wave>>1, wc = wave&1;
  f32x4 acc[4][4] = {};
  float nacc[4] = {0.f,0.f,0.f,0.f};
  for (int s=0;s<8;s++){
    const int k0 = s<<6;
    #pragma unroll
    for (int q=0;q<4;q++){
      const int i = (wave<<2)+q;
      const int row = (i<<3) + (lane>>3);
      const int cd = (lane&7) ^ (row&7);
      const float* src = Sb + row*512 + k0 + (cd<<3);
      const f32x4 va = *(const f32x4*)src;
      const f32x4 vb = *(const f32x4*)(src+4);
      u16x8 t;
      #pragma unroll
      for (int e=0;e<4;e++){ t[e]=f2b(va[e]); t[4+e]=f2b(vb[e]); }
      #pragma unroll
      for (int e=0;e<8;e++){ float fv=b2f(t[e]); nacc[q]=fmaf(fv,fv,nacc[q]); }
      *(u16x8*)((char*)sA + i*1024 + lane*16) = t;
    }
    __syncthreads();
    #pragma unroll
    for (int kh=0;kh<2;kh++){
      bf16x8 a_[4], b_[4];
      #pragma unroll
      for (int i=0;i<4;i++){
        const int ra = (wr<<6)+(i<<4)+lrow;
        a_[i] = *(const bf16x8*)(sA + ra*64 + ((((kh<<2)+lg)^(ra&7))<<3));
        const int rb = (wc<<6)+(i<<4)+lrow;
        b_[i] = *(const bf16x8*)(sA + rb*64 + ((((kh<<2)+lg)^(rb&7))<<3));
      }
      #pragma unroll
      for (int i=0;i<4;i++)
        #pragma unroll
        for (int j=0;j<4;j++)
          acc[i][j] = __builtin_amdgcn_mfma_f32_16x16x32_bf16(a_[i], b_[j], acc[i][j], 0,0,0);
    }
    __syncthreads();
  }
  #pragma unroll
  for (int q=0;q<4;q++){
    float v = nacc[q];
    v += __shfl_xor(v,1); v += __shfl_xor(v,2); v += __shfl_xor(v,4);
    if ((lane&7)==0) nrm[((wave<<2)+q)*8 + (lane>>3)] = v;
  }
  __syncthreads();
  #pragma unroll
  for (int j=0;j<4;j++){
    const int col = (wc<<6)+(j<<4)+lrow;
    const float nbv = nrm[col];
    #pragma unroll
    for (int i=0;i<4;i++){
      const int row0 = (wr<<6)+(i<<4)+(lg<<2);
      u16x4 hi4, lo4;
      #pragma unroll
      for (int r=0;r<4;r++){
        float n2 = nrm[row0+r] + nbv - 2.0f*acc[i][j][r];
        float sv = sqrtf(fmaxf(n2, 1e-6f));
        u16 h = f2b(sv); hi4[r] = h;
        lo4[r] = f2b(sv - b2f(h));
      }
      const int sa = col*256 + ((((row0>>3)^col)&15)<<4) + ((row0&7)<<1);
      char* base = SHL + (size_t)b*65536;
      *(u16x4*)(base + sa) = hi4;
      *(u16x4*)(base + 32768 + sa) = lo4;
    }
  }
}

// ---------------------------------------------------------------------------
// mu/nu + base-2 logs. 256 blocks x 128 threads.
__global__ void prep_k(const float* __restrict__ mask_q, const float* __restrict__ mask_r,
                       float* __restrict__ lmu2, float* __restrict__ lnu2,
                       float* __restrict__ mu, float* __restrict__ nu){
  int b = blockIdx.x, t = threadIdx.x;
  __shared__ float red[4];
  float mq = mask_q[b*128+t], mr = mask_r[b*128+t];
  float s1 = mq, s2 = mr;
  #pragma unroll
  for (int off=1;off<64;off<<=1){ s1 += __shfl_xor(s1,off); s2 += __shfl_xor(s2,off); }
  if ((t&63)==0){ red[t>>6] = s1; red[2+(t>>6)] = s2; }
  __syncthreads();
  float sumq = red[0]+red[1], sumr = red[2]+red[3];
  float muv = mq/(sumq+1e-8f), nuv = mr/(sumr+1e-8f);
  lmu2[b*128+t] = __log2f(fmaxf(muv,1e-8f));
  lnu2[b*128+t] = __log2f(fmaxf(nuv,1e-8f));
  mu[b*128+t] = muv;
  nu[b*128+t] = nuv;
}

// ---------------------------------------------------------------------------
// 5-iter FGW loop, 512 threads/block (8 waves), base-2 domain (log-domain LSE).
// C resident in registers across outers; t1/t2 from LDS hi/lo planes.
// Sinkhorn dual layouts: Layout-R thread owns row kR=16w+l15, cols 16q+4lg+e;
// Layout-C owns col nC=kR, rows 16q+4lg+e.
__global__ __launch_bounds__(512,1) void fgw_loop_k(
    const char* __restrict__ SQHL, const char* __restrict__ SRHL,
    const float* __restrict__ C_g,
    const float* __restrict__ MU, const float* __restrict__ NU,
    const float* __restrict__ LMU2, const float* __restrict__ LNU2,
    const float* __restrict__ log_eps,
    float* __restrict__ T_out, float* __restrict__ cost_out, float* __restrict__ sim_out)
{
  __shared__ __align__(16) char bufT[65536];   // T planes / TSr^T planes / lk row-major
  __shared__ __align__(16) char bufS[65536];   // Sr planes / Sq planes / lk col-major
  __shared__ __align__(16) float avs[128], bvs[128], t1s[128], t2s[128];
  __shared__ __align__(16) float lus[128], lvs[128];
  __shared__ float redc[8];

  const int b = blockIdx.x, tid = threadIdx.x;
  const int w = tid>>6, lane = tid&63, l15 = lane&15, lg = lane>>4;
  const char* SqHLb = SQHL + (size_t)b*65536;
  const char* SrHLb = SRHL + (size_t)b*65536;
  const float* Cb   = C_g + (size_t)b*16384;
  const float* MUb  = MU + b*128;
  const float* NUb  = NU + b*128;

  float eps = __expf(log_eps[0]); eps = fminf(fmaxf(eps,0.01f),0.5f);
  const float rho = 0.1f/(0.1f+eps);
  const float hscale = 0.5f*1.4426950408889634f/eps;   // 0.5*log2(e)/eps

  const int kR = 16*w + l15;       // Layout-R row / Layout-C col
  const int n0 = 16*w + 4*lg;      // fragment n base
  const float lmu2R = LMU2[b*128+kR];
  const float lnu2C = LNU2[b*128+kR];

  const int rowA256 = (16*w + l15)*256;
  const int glo2 = lg ^ (l15 & 3);
  const int ghi2 = l15 & 12;
  const int wtail = l15*256 + ((((2*w + (lg>>1)) ^ l15)&15)<<4) + ((lg&1)<<3);

  // resident C fragments, pre-scaled: Cf2 = -hscale * C[16kt+l15][n0..n0+3]
  f32x4 Cf2[8];
  #pragma unroll
  for (int kt=0;kt<8;kt++)
    Cf2[kt] = -hscale * (*(const f32x4*)(Cb + (size_t)(16*kt+l15)*128 + n0));

  f32x4 lkR[8], lkC[8];
  float luR = 0.f, lvC = 0.f;

  for (int outer=0; outer<5; outer++){
    // ---- P0: stage Sr; T planes + avs/bvs
    #pragma unroll
    for (int r2=0;r2<8;r2++)
      gload_lds16(SrHLb + r2*8192 + tid*16, bufS + r2*8192 + tid*16);
    {
      f32x4 avp = {0.f,0.f,0.f,0.f};
      float bvp = 0.f;
      #pragma unroll
      for (int q=0;q<8;q++){
        f32x4 TR, TC;
        if (outer==0){
          const f32x4 nu4 = *(const f32x4*)(NUb + 16*q + 4*lg);
          const f32x4 mu4 = *(const f32x4*)(MUb + 16*q + 4*lg);
          const float muR = MUb[kR], nuC = NUb[kR];
          TR = muR*nu4; TC = mu4*nuC;
        } else {
          const f32x4 lv4 = *(const f32x4*)&lvs[16*q + 4*lg];
          const f32x4 lu4 = *(const f32x4*)&lus[16*q + 4*lg];
          #pragma unroll
          for (int e=0;e<4;e++){
            TR[e] = exp2f(lkR[q][e] + luR + lv4[e]);
            TC[e] = exp2f(lkC[q][e] + lu4[e] + lvC);
          }
        }
        u16x4 hi4, lo4;
        #pragma unroll
        for (int e=0;e<4;e++){
          u16 h = f2b(TR[e]); hi4[e] = h;
          lo4[e] = f2b(TR[e] - b2f(h));
        }
        const int sa = kR*256 + ((((2*q+(lg>>1)) ^ l15)&15)<<4) + ((lg&1)<<3);
        *(u16x4*)(bufT + sa) = hi4;
        *(u16x4*)(bufT + 32768 + sa) = lo4;
        avp += TR;
        bvp += TC[0]+TC[1]+TC[2]+TC[3];
      }
      float av = avp[0]+avp[1]+avp[2]+avp[3];
      av += __shfl_xor(av,16); av += __shfl_xor(av,32);
      bvp += __shfl_xor(bvp,16); bvp += __shfl_xor(bvp,32);
      if (lg==0){ avs[kR] = av; bvs[kR] = bvp; }
    }
    __syncthreads();   // C: Sr staged, T planes, avs/bvs

    // ---- P1: t2 from Sr planes (bufS) + bvs; phase A MFMA
    {
      const int p = tid>>2, sub = tid&3;     // row p, m in [32sub,32sub+32)
      float s2 = 0.f;
      #pragma unroll
      for (int gg=0; gg<4; gg++){
        const int g = 4*sub+gg;
        const int off = p*256 + (((g ^ (p&15))&15)<<4);
        const u16x8 h8 = *(const u16x8*)(bufS + off);
        const u16x8 l8 = *(const u16x8*)(bufS + 32768 + off);
        const f32x4 bva = *(const f32x4*)&bvs[8*g];
        const f32x4 bvb = *(const f32x4*)&bvs[8*g+4];
        #pragma unroll
        for (int e=0;e<4;e++){
          float x = b2f(h8[e]) + b2f(l8[e]);
          s2 = fmaf(bva[e], x*x, s2);
          float y2 = b2f(h8[4+e]) + b2f(l8[4+e]);
          s2 = fmaf(bvb[e], y2*y2, s2);
        }
      }
      s2 += __shfl_xor(s2,1); s2 += __shfl_xor(s2,2);
      if (sub==0) t2s[p] = s2;
    }
    f32x4 acc1[8] = {};
    #pragma unroll
    for (int qt=0;qt<4;qt++){
      const int colOff = (((4*qt) ^ ghi2) | glo2) << 4;
      const bf16x8 ahi = *(const bf16x8*)(bufT + rowA256 + colOff);
      const bf16x8 alo = *(const bf16x8*)(bufT + 32768 + rowA256 + colOff);
      const int bbase = l15*256 + colOff;
      #pragma unroll
      for (int nt=0;nt<8;nt++){
        const bf16x8 bhi = *(const bf16x8*)(bufS + nt*4096 + bbase);
        const bf16x8 blo = *(const bf16x8*)(bufS + 32768 + nt*4096 + bbase);
        acc1[nt] = __builtin_amdgcn_mfma_f32_16x16x32_bf16(ahi, bhi, acc1[nt], 0,0,0);
        acc1[nt] = __builtin_amdgcn_mfma_f32_16x16x32_bf16(ahi, blo, acc1[nt], 0,0,0);
        acc1[nt] = __builtin_amdgcn_mfma_f32_16x16x32_bf16(alo, bhi, acc1[nt], 0,0,0);
      }
    }
    __syncthreads();   // E: phase-A reads done, t2s written

    // ---- P2: stage Sq; write TSr^T planes
    #pragma unroll
    for (int r2=0;r2<8;r2++)
      gload_lds16(SqHLb + r2*8192 + tid*16, bufS + r2*8192 + tid*16);
    #pragma unroll
    for (int nt=0;nt<8;nt++){
      u16x4 hi4, lo4;
      #pragma unroll
      for (int r=0;r<4;r++){
        u16 h = f2b(acc1[nt][r]); hi4[r] = h;
        lo4[r] = f2b(acc1[nt][r] - b2f(h));
      }
      const int sa = nt*4096 + wtail;
      *(u16x4*)(bufT + sa) = hi4;
      *(u16x4*)(bufT + 32768 + sa) = lo4;
    }
    __syncthreads();   // G: Sq staged + TSr^T planes

    // ---- P3: t1 from Sq planes (bufS) + avs; phase B MFMA
    {
      const int p = tid>>2, sub = tid&3;
      float s1 = 0.f;
      #pragma unroll
      for (int gg=0; gg<4; gg++){
        const int g = 4*sub+gg;
        const int off = p*256 + (((g ^ (p&15))&15)<<4);
        const u16x8 h8 = *(const u16x8*)(bufS + off);
        const u16x8 l8 = *(const u16x8*)(bufS + 32768 + off);
        const f32x4 ava = *(const f32x4*)&avs[8*g];
        const f32x4 avb = *(const f32x4*)&avs[8*g+4];
        #pragma unroll
        for (int e=0;e<4;e++){
          float x = b2f(h8[e]) + b2f(l8[e]);
          s1 = fmaf(ava[e], x*x, s1);
          float y2 = b2f(h8[4+e]) + b2f(l8[4+e]);
          s1 = fmaf(avb[e], y2*y2, s1);
        }
      }
      s1 += __shfl_xor(s1,1); s1 += __shfl_xor(s1,2);
      if (sub==0) t1s[p] = s1;
    }
    f32x4 acc2[8] = {};
    #pragma unroll
    for (int qt=0;qt<4;qt++){
      const int colOff = (((4*qt) ^ ghi2) | glo2) << 4;
      const bf16x8 ahi = *(const bf16x8*)(bufT + rowA256 + colOff);
      const bf16x8 alo = *(const bf16x8*)(bufT + 32768 + rowA256 + colOff);
      const int bbase = l15*256 + colOff;
      #pragma unroll
      for (int kt=0;kt<8;kt++){
        const bf16x8 bhi = *(const bf16x8*)(bufS + kt*4096 + bbase);
        const bf16x8 blo = *(const bf16x8*)(bufS + 32768 + kt*4096 + bbase);
        acc2[kt] = __builtin_amdgcn_mfma_f32_16x16x32_bf16(ahi, bhi, acc2[kt], 0,0,0);
        acc2[kt] = __builtin_amdgcn_mfma_f32_16x16x32_bf16(ahi, blo, acc2[kt], 0,0,0);
        acc2[kt] = __builtin_amdgcn_mfma_f32_16x16x32_bf16(alo, bhi, acc2[kt], 0,0,0);
      }
    }
    __syncthreads();   // I: phase-B reads done; t1s/t2s visible

    // ---- P4: lk build (regs) + bounce writes
    f32x4 lkf[8];
    {
      const f32x4 t24 = *(const f32x4*)&t2s[n0];
      #pragma unroll
      for (int kt=0;kt<8;kt++){
        const float t1v = t1s[16*kt+l15];
        lkf[kt] = Cf2[kt] + hscale*(2.0f*acc2[kt] - t1v - t24);
      }
    }
    #pragma unroll
    for (int kt=0;kt<8;kt++){
      const int row = 16*kt + l15;
      const int gp = ((4*w+lg) ^ (row&31)) & 31;
      *(f32x4*)(bufT + row*512 + gp*16) = lkf[kt];
      #pragma unroll
      for (int e=0;e<4;e++){
        const int n = n0 + e;
        const int gt = ((4*kt + (l15>>2)) ^ (n&31)) & 31;
        *(float*)(bufS + n*512 + gt*16 + (l15&3)*4) = lkf[kt][e];
      }
    }
    __syncthreads();   // K
    #pragma unroll
    for (int q=0;q<8;q++){
      const int g1 = ((4*q+lg) ^ (kR&31)) & 31;
      lkR[q] = *(const f32x4*)(bufT + kR*512 + g1*16);
      lkC[q] = *(const f32x4*)(bufS + kR*512 + g1*16);
    }

    // ---- Sinkhorn: 10 iterations, base-2
    for (int it=0; it<10; it++){
      f32x4 y[8];
      #pragma unroll
      for (int q=0;q<8;q++){
        y[q] = lkR[q];
        if (it) y[q] += *(const f32x4*)&lvs[16*q+4*lg];
      }
      f32x4 m4 = vmax4(vmax4(vmax4(y[0],y[1]),vmax4(y[2],y[3])),
                       vmax4(vmax4(y[4],y[5]),vmax4(y[6],y[7])));
      float mx = fmaxf(fmaxf(m4[0],m4[1]), fmaxf(m4[2],m4[3]));
      mx = fmaxf(mx,__shfl_xor(mx,16)); mx = fmaxf(mx,__shfl_xor(mx,32));
      f32x4 s4 = {0.f,0.f,0.f,0.f};
      #pragma unroll
      for (int q=0;q<8;q++){
        #pragma unroll
        for (int e=0;e<4;e++) s4[e] += exp2f(y[q][e]-mx);
      }
      float s = s4[0]+s4[1]+s4[2]+s4[3];
      s += __shfl_xor(s,16); s += __shfl_xor(s,32);
      luR = rho*(lmu2R - (mx + __log2f(s)));
      if (lg==0) lus[kR] = luR;
      __syncthreads();
      #pragma unroll
      for (int q=0;q<8;q++)
        y[q] = lkC[q] + *(const f32x4*)&lus[16*q+4*lg];
      m4 = vmax4(vmax4(vmax4(y[0],y[1]),vmax4(y[2],y[3])),
                 vmax4(vmax4(y[4],y[5]),vmax4(y[6],y[7])));
      mx = fmaxf(fmaxf(m4[0],m4[1]), fmaxf(m4[2],m4[3]));
      mx = fmaxf(mx,__shfl_xor(mx,16)); mx = fmaxf(mx,__shfl_xor(mx,32));
      s4 = (f32x4){0.f,0.f,0.f,0.f};
      #pragma unroll
      for (int q=0;q<8;q++){
        #pragma unroll
        for (int e=0;e<4;e++) s4[e] += exp2f(y[q][e]-mx);
      }
      s = s4[0]+s4[1]+s4[2]+s4[3];
      s += __shfl_xor(s,16); s += __shfl_xor(s,32);
      lvC = rho*(lnu2C - (mx + __log2f(s)));
      if (lg==0) lvs[kR] = lvC;
      __syncthreads();
    }

    if (outer==4){
      float cp = 0.f;
      float* Tb = T_out + (size_t)b*16384;
      #pragma unroll
      for (int q=0;q<8;q++){
        const f32x4 lv4 = *(const f32x4*)&lvs[16*q+4*lg];
        f32x4 t;
        #pragma unroll
        for (int e=0;e<4;e++) t[e] = exp2f(lkR[q][e] + luR + lv4[e]);
        *(f32x4*)(Tb + kR*128 + 16*q + 4*lg) = t;
        const f32x4 pr = t*lkR[q];
        cp += pr[0]+pr[1]+pr[2]+pr[3];
      }
      cp *= -eps*0.6931471805599453f;        // cost = sum T * (-eps*ln2*lk2)
      #pragma unroll
      for (int off=1;off<64;off<<=1) cp += __shfl_xor(cp, off);
      if (lane==0) redc[w] = cp;
      __syncthreads();
      if (tid==0){
        float tot = 0.f;
        #pragma unroll
        for (int w2=0;w2<8;w2++) tot += redc[w2];
        cost_out[b] = tot;
        sim_out[b]  = 1.0f/(1.0f + __expf(tot));
      }
    }
  }
}

// ---------------------------------------------------------------------------
extern "C" void kernel_launch(void* const* d_in, const int* in_sizes, int n_in,
                              void* d_out, int out_size, void* d_ws, size_t ws_size,
                              hipStream_t stream){
  const float* sq      = (const float*)d_in[0];
  const float* sr      = (const float*)d_in[1];
  const float* mask_q  = (const float*)d_in[2];
  const float* mask_r  = (const float*)d_in[3];
  const float* cq      = (const float*)d_in[4];
  const float* cr      = (const float*)d_in[5];
  const float* W1      = (const float*)d_in[6];
  const float* b1      = (const float*)d_in[7];
  const float* W2      = (const float*)d_in[8];
  const float* b2      = (const float*)d_in[9];
  const float* log_eps = (const float*)d_in[10];

  float* out  = (float*)d_out;
  float* sim  = out;                 // [256]
  float* Tm   = out + 256;           // [256][128][128]
  float* Cm   = Tm + 4194304;        // [256][128][128]
  float* cost = Cm + 4194304;        // [256]

  char* ws = (char*)d_ws;
  size_t off = 0;
  auto alloc = [&](size_t bytes)->void*{ void* p = ws + off; off += (bytes+255)&~(size_t)255; return p; };
  u16*   PQ  = (u16*)  alloc(67108864);   // P bf16 (65536x512); later loop planes
  u16*   HQ  = (u16*)  alloc(67108864);   // hidden H bf16 (65536x512)
  u16*   W1T = (u16*)  alloc(524288);
  u16*   W2T = (u16*)  alloc(524288);
  float* NP  = (float*)alloc(262144);     // row norms of P (65536), atomic-accumulated
  float* LMU = (float*)alloc(131072);
  float* LNU = (float*)alloc(131072);
  float* MUA = (float*)alloc(131072);
  float* NUA = (float*)alloc(131072);
  (void)ws_size; (void)in_sizes; (void)n_in; (void)out_size;

  // After pdist0 consumes P, its region is reused for the loop planes:
  char* SQHL = (char*)PQ;                  // 16MB bf16 hi/lo Sq planes
  char* SRHL = (char*)PQ + 16777216;       // 16MB bf16 hi/lo Sr planes

  prepw_k<<<1024,256,0,stream>>>(W1, W1T);
  prepw_k<<<1024,256,0,stream>>>(W2, W2T);
  gemm_k<1,0,1><<<2048,256,0,stream>>>(nullptr, sq, sr, W1T, b1, HQ, nullptr);
  hipMemsetAsync(NP, 0, 262144, stream);
  gemm_k<0,1,0><<<2048,256,0,stream>>>(HQ, nullptr, nullptr, W2T, b2, PQ, NP);
  pdist0_k<<<256,256,0,stream>>>(PQ, PQ + (size_t)32768*512, NP, NP + 32768, Cm);
  pdistS_k<<<256,256,0,stream>>>(cq, SQHL);
  pdistS_k<<<256,256,0,stream>>>(cr, SRHL);
  prep_k<<<256,128,0,stream>>>(mask_q, mask_r, LMU, LNU, MUA, NUA);
  fgw_loop_k<<<256,512,0,stream>>>(SQHL, SRHL, Cm, MUA, NUA, LMU, LNU,
                                   log_eps, Tm, cost, sim);
}

// Round 9
// 435.120 us; speedup vs baseline: 1.2435x; 1.0494x over previous
//
#include <hip/hip_runtime.h>
#include <math.h>

typedef unsigned short u16;
typedef __attribute__((ext_vector_type(4))) float f32x4;
typedef __attribute__((ext_vector_type(8))) short bf16x8;
typedef __attribute__((ext_vector_type(4))) unsigned short u16x4;
typedef __attribute__((ext_vector_type(8))) unsigned short u16x8;

#define DEVI static __device__ __forceinline__

DEVI float b2f(u16 u){ union{float f; unsigned i;} v; v.i = ((unsigned)u)<<16; return v.f; }
DEVI u16 f2b(float f){ union{float f; unsigned i;} v; v.f=f;
  unsigned r = v.i + 0x7fffu + ((v.i>>16)&1u); return (u16)(r>>16); }

DEVI void gload_lds16(const void* g, void* l){
  __builtin_amdgcn_global_load_lds((const __attribute__((address_space(1))) void*)g,
                                   (__attribute__((address_space(3))) void*)l, 16, 0, 0);
}

// LDS-only barrier: waits DS ops, does NOT drain vmcnt (keeps prefetch in flight)
DEVI void lds_bar(){ asm volatile("s_waitcnt lgkmcnt(0)\n\ts_barrier" ::: "memory"); }

DEVI f32x4 vmax4(f32x4 a, f32x4 b){
  f32x4 r; r[0]=fmaxf(a[0],b[0]); r[1]=fmaxf(a[1],b[1]);
  r[2]=fmaxf(a[2],b[2]); r[3]=fmaxf(a[3],b[3]); return r;
}

// ---------------------------------------------------------------------------
// Merged prologue: blocks [0,2048): W1/W2 -> bf16 [c][k]; blocks [2048,2176):
// mu/nu + base-2 logs (2 batches per 256-thread block).
__global__ void prologue_k(const float* __restrict__ W1, const float* __restrict__ W2,
                           u16* __restrict__ W1T, u16* __restrict__ W2T,
                           const float* __restrict__ mask_q, const float* __restrict__ mask_r,
                           float* __restrict__ lmu2, float* __restrict__ lnu2,
                           float* __restrict__ mu, float* __restrict__ nu){
  const int blk = blockIdx.x;
  if (blk < 2048){
    const float* W = (blk<1024)? W1 : W2;
    u16* Wt = (blk<1024)? W1T : W2T;
    int id = (blk&1023)*256 + threadIdx.x;
    int k = id>>9, c = id&511;
    Wt[c*512 + k] = f2b(W[id]);
  } else {
    __shared__ float red[2][4];
    const int h = threadIdx.x>>7, t = threadIdx.x&127;
    const int b = (blk-2048)*2 + h;
    float mq = mask_q[b*128+t], mr = mask_r[b*128+t];
    float s1 = mq, s2 = mr;
    #pragma unroll
    for (int off=1;off<64;off<<=1){ s1 += __shfl_xor(s1,off); s2 += __shfl_xor(s2,off); }
    if ((t&63)==0){ red[h][(t>>6)&1] = s1; red[h][2+((t>>6)&1)] = s2; }
    __syncthreads();
    float sumq = red[h][0]+red[h][1], sumr = red[h][2]+red[h][3];
    float muv = mq/(sumq+1e-8f), nuv = mr/(sumr+1e-8f);
    lmu2[b*128+t] = __log2f(fmaxf(muv,1e-8f));
    lnu2[b*128+t] = __log2f(fmaxf(nuv,1e-8f));
    mu[b*128+t] = muv;
    nu[b*128+t] = nuv;
  }
}

// ---------------------------------------------------------------------------
// OUT[r][c] = act(sum_k X[r][k]*W[k][c] + bias[c]); Wt bf16 [c][k].
// AF32: A-tile reg-staged from f32 sources. NORM: row norms via atomicAdd.
template<int ACT, int NORM, int AF32>
__global__ __launch_bounds__(256) void gemm_k(const u16* __restrict__ X,
    const float* __restrict__ Xf1, const float* __restrict__ Xf2,
    const u16* __restrict__ Wt, const float* __restrict__ bias, u16* __restrict__ OUT,
    float* __restrict__ NP){
  __shared__ __align__(16) u16 sA[128*64];
  __shared__ __align__(16) u16 sB[128*64];
  const int tid = threadIdx.x, wave = tid>>6, lane = tid&63;
  const int bid = (blockIdx.x&7)*256 + (blockIdx.x>>3);
  const int rblk = bid>>2, cb = (bid&3)<<7;
  const u16* Xb = AF32 ? nullptr : (X + (size_t)rblk*(128*512));
  const float* Xbf = AF32 ? (rblk<256 ? Xf1 + (size_t)rblk*65536
                                      : Xf2 + (size_t)(rblk-256)*65536) : nullptr;
  const u16* Wb = Wt + (size_t)cb*512;
  const int lrow = lane&15, lg = lane>>4, wr = wave>>1, wc = wave&1;
  f32x4 acc[4][4] = {};
  for (int s=0;s<8;s++){
    const int k0 = s<<6;
    #pragma unroll
    for (int q=0;q<4;q++){
      const int i = (wave<<2)+q;
      const int row = (i<<3) + (lane>>3);
      const int cd = (lane&7) ^ (row&7);
      if (AF32){
        const float* src = Xbf + row*512 + k0 + (cd<<3);
        const f32x4 va = *(const f32x4*)src;
        const f32x4 vb = *(const f32x4*)(src+4);
        u16x8 t;
        #pragma unroll
        for (int e=0;e<4;e++){ t[e]=f2b(va[e]); t[4+e]=f2b(vb[e]); }
        *(u16x8*)((char*)sA + i*1024 + lane*16) = t;
      } else {
        gload_lds16(Xb + row*512 + k0 + (cd<<3), sA + i*512);
      }
      gload_lds16(Wb + row*512 + k0 + (cd<<3), sB + i*512);
    }
    __syncthreads();
    #pragma unroll
    for (int kh=0;kh<2;kh++){
      bf16x8 a_[4], b_[4];
      #pragma unroll
      for (int i=0;i<4;i++){
        const int ra = (wr<<6)+(i<<4)+lrow;
        a_[i] = *(const bf16x8*)(sA + ra*64 + ((((kh<<2)+lg)^(ra&7))<<3));
        const int rb = (wc<<6)+(i<<4)+lrow;
        b_[i] = *(const bf16x8*)(sB + rb*64 + ((((kh<<2)+lg)^(rb&7))<<3));
      }
      #pragma unroll
      for (int i=0;i<4;i++)
        #pragma unroll
        for (int j=0;j<4;j++)
          acc[i][j] = __builtin_amdgcn_mfma_f32_16x16x32_bf16(a_[i], b_[j], acc[i][j], 0,0,0);
    }
    __syncthreads();
  }
  float nacc[4][4];
  if (NORM){
    #pragma unroll
    for (int i=0;i<4;i++)
      #pragma unroll
      for (int r=0;r<4;r++) nacc[i][r]=0.f;
  }
  #pragma unroll
  for (int j=0;j<4;j++){
    const int col = cb + (wc<<6) + (j<<4) + lrow;
    const float bv = bias[col];
    #pragma unroll
    for (int i=0;i<4;i++){
      const int row0 = (rblk<<7) + (wr<<6) + (i<<4) + (lg<<2);
      #pragma unroll
      for (int r=0;r<4;r++){
        float v = acc[i][j][r] + bv;
        if (ACT) v = fmaxf(v, 0.f);
        u16 pb = f2b(v);
        OUT[(size_t)(row0+r)*512 + col] = pb;
        if (NORM){ float fv = b2f(pb); nacc[i][r] += fv*fv; }
      }
    }
  }
  if (NORM){
    #pragma unroll
    for (int i=0;i<4;i++)
      #pragma unroll
      for (int r=0;r<4;r++){
        float v = nacc[i][r];
        v += __shfl_xor(v,1); v += __shfl_xor(v,2);
        v += __shfl_xor(v,4); v += __shfl_xor(v,8);
        if (lrow==0)
          atomicAdd(NP + (rblk<<7) + (wr<<6) + (i<<4) + (lg<<2) + r, v);
      }
  }
}

// ---------------------------------------------------------------------------
// pdist0: C[b][k][m] = sqrt(max(na+nb-2*dot,1e-6)); bf16 inputs, ext. norms.
__global__ __launch_bounds__(256) void pdist0_k(const u16* __restrict__ Xa,
    const u16* __restrict__ Xb2, const float* __restrict__ na, const float* __restrict__ nb,
    float* __restrict__ OUT){
  __shared__ __align__(16) u16 sA[128*64];
  __shared__ __align__(16) u16 sB[128*64];
  const int tid = threadIdx.x, wave = tid>>6, lane = tid&63;
  const int b = blockIdx.x;
  const u16* Ab = Xa + (size_t)b*(128*512);
  const u16* Bb = Xb2 + (size_t)b*(128*512);
  const int lrow = lane&15, lg = lane>>4, wr = wave>>1, wc = wave&1;
  f32x4 acc[4][4] = {};
  for (int s=0;s<8;s++){
    const int k0 = s<<6;
    #pragma unroll
    for (int q=0;q<4;q++){
      const int i = (wave<<2)+q;
      const int row = (i<<3) + (lane>>3);
      const int cd = (lane&7) ^ (row&7);
      gload_lds16(Ab + row*512 + k0 + (cd<<3), sA + i*512);
      gload_lds16(Bb + row*512 + k0 + (cd<<3), sB + i*512);
    }
    __syncthreads();
    #pragma unroll
    for (int kh=0;kh<2;kh++){
      bf16x8 a_[4], b_[4];
      #pragma unroll
      for (int i=0;i<4;i++){
        const int ra = (wr<<6)+(i<<4)+lrow;
        a_[i] = *(const bf16x8*)(sA + ra*64 + ((((kh<<2)+lg)^(ra&7))<<3));
        const int rb = (wc<<6)+(i<<4)+lrow;
        b_[i] = *(const bf16x8*)(sB + rb*64 + ((((kh<<2)+lg)^(rb&7))<<3));
      }
      #pragma unroll
      for (int i=0;i<4;i++)
        #pragma unroll
        for (int j=0;j<4;j++)
          acc[i][j] = __builtin_amdgcn_mfma_f32_16x16x32_bf16(a_[i], b_[j], acc[i][j], 0,0,0);
    }
    __syncthreads();
  }
  #pragma unroll
  for (int j=0;j<4;j++){
    const int col = (wc<<6)+(j<<4)+lrow;
    const float nbv = nb[b*128+col];
    #pragma unroll
    for (int i=0;i<4;i++){
      const int row0 = (wr<<6)+(i<<4)+(lg<<2);
      #pragma unroll
      for (int r=0;r<4;r++){
        float n2 = na[b*128+row0+r] + nbv - 2.0f*acc[i][j][r];
        OUT[(size_t)b*16384 + (size_t)(row0+r)*128 + col] = sqrtf(fmaxf(n2, 1e-6f));
      }
    }
  }
}

// pdistS2: both symmetric self-distance plane sets in one launch (512 blocks).
__global__ __launch_bounds__(256) void pdistS2_k(const float* __restrict__ cq,
    const float* __restrict__ cr, char* __restrict__ SQHL, char* __restrict__ SRHL){
  __shared__ __align__(16) u16 sA[128*64];
  __shared__ float nrm[128];
  const int tid = threadIdx.x, wave = tid>>6, lane = tid&63;
  const int b = blockIdx.x & 255;
  const float* Sb = ((blockIdx.x<256)? cq : cr) + (size_t)b*65536;
  char* SHL = (blockIdx.x<256)? SQHL : SRHL;
  const int lrow = lane&15, lg = lane>>4, wr = wave>>1, wc = wave&1;
  f32x4 acc[4][4] = {};
  float nacc[4] = {0.f,0.f,0.f,0.f};
  for (int s=0;s<8;s++){
    const int k0 = s<<6;
    #pragma unroll
    for (int q=0;q<4;q++){
      const int i = (wave<<2)+q;
      const int row = (i<<3) + (lane>>3);
      const int cd = (lane&7) ^ (row&7);
      const float* src = Sb + row*512 + k0 + (cd<<3);
      const f32x4 va = *(const f32x4*)src;
      const f32x4 vb = *(const f32x4*)(src+4);
      u16x8 t;
      #pragma unroll
      for (int e=0;e<4;e++){ t[e]=f2b(va[e]); t[4+e]=f2b(vb[e]); }
      #pragma unroll
      for (int e=0;e<8;e++){ float fv=b2f(t[e]); nacc[q]=fmaf(fv,fv,nacc[q]); }
      *(u16x8*)((char*)sA + i*1024 + lane*16) = t;
    }
    __syncthreads();
    #pragma unroll
    for (int kh=0;kh<2;kh++){
      bf16x8 a_[4], b_[4];
      #pragma unroll
      for (int i=0;i<4;i++){
        const int ra = (wr<<6)+(i<<4)+lrow;
        a_[i] = *(const bf16x8*)(sA + ra*64 + ((((kh<<2)+lg)^(ra&7))<<3));
        const int rb = (wc<<6)+(i<<4)+lrow;
        b_[i] = *(const bf16x8*)(sA + rb*64 + ((((kh<<2)+lg)^(rb&7))<<3));
      }
      #pragma unroll
      for (int i=0;i<4;i++)
        #pragma unroll
        for (int j=0;j<4;j++)
          acc[i][j] = __builtin_amdgcn_mfma_f32_16x16x32_bf16(a_[i], b_[j], acc[i][j], 0,0,0);
    }
    __syncthreads();
  }
  #pragma unroll
  for (int q=0;q<4;q++){
    float v = nacc[q];
    v += __shfl_xor(v,1); v += __shfl_xor(v,2); v += __shfl_xor(v,4);
    if ((lane&7)==0) nrm[((wave<<2)+q)*8 + (lane>>3)] = v;
  }
  __syncthreads();
  #pragma unroll
  for (int j=0;j<4;j++){
    const int col = (wc<<6)+(j<<4)+lrow;
    const float nbv = nrm[col];
    #pragma unroll
    for (int i=0;i<4;i++){
      const int row0 = (wr<<6)+(i<<4)+(lg<<2);
      u16x4 hi4, lo4;
      #pragma unroll
      for (int r=0;r<4;r++){
        float n2 = nrm[row0+r] + nbv - 2.0f*acc[i][j][r];
        float sv = sqrtf(fmaxf(n2, 1e-6f));
        u16 h = f2b(sv); hi4[r] = h;
        lo4[r] = f2b(sv - b2f(h));
      }
      const int sa = col*256 + ((((row0>>3)^col)&15)<<4) + ((row0&7)<<1);
      char* base = SHL + (size_t)b*65536;
      *(u16x4*)(base + sa) = hi4;
      *(u16x4*)(base + 32768 + sa) = lo4;
    }
  }
}

// ---------------------------------------------------------------------------
// 5-iter FGW loop, 512 threads/block, base-2 log-domain Sinkhorn.
// lk exchange via linear XOR-slotted buffer; Sr prefetched during Sinkhorn;
// Sinkhorn barriers are lgkm-only (prefetch stays in flight).
__global__ __launch_bounds__(512,1) void fgw_loop_k(
    const char* __restrict__ SQHL, const char* __restrict__ SRHL,
    const float* __restrict__ C_g,
    const float* __restrict__ MU, const float* __restrict__ NU,
    const float* __restrict__ LMU2, const float* __restrict__ LNU2,
    const float* __restrict__ log_eps,
    float* __restrict__ T_out, float* __restrict__ cost_out, float* __restrict__ sim_out)
{
  __shared__ __align__(16) char bufT[65536];   // T planes / TSr^T planes / lk exchange
  __shared__ __align__(16) char bufS[65536];   // Sr planes / Sq planes (prefetch target)
  __shared__ __align__(16) float avs[128], bvs[128], t1s[128], t2s[128];
  __shared__ __align__(16) float lus[128], lvs[128];
  __shared__ float redc[8];

  const int b = blockIdx.x, tid = threadIdx.x;
  const int w = tid>>6, lane = tid&63, l15 = lane&15, lg = lane>>4;
  const char* SqHLb = SQHL + (size_t)b*65536;
  const char* SrHLb = SRHL + (size_t)b*65536;
  const float* Cb   = C_g + (size_t)b*16384;
  const float* MUb  = MU + b*128;
  const float* NUb  = NU + b*128;

  float eps = __expf(log_eps[0]); eps = fminf(fmaxf(eps,0.01f),0.5f);
  const float rho = 0.1f/(0.1f+eps);
  const float hscale = 0.5f*1.4426950408889634f/eps;   // 0.5*log2(e)/eps

  const int kR = 16*w + l15;       // Layout-R row / Layout-C col
  const int n0 = 16*w + 4*lg;      // fragment n base
  const float lmu2R = LMU2[b*128+kR];
  const float lnu2C = LNU2[b*128+kR];

  const int rowA256 = (16*w + l15)*256;
  const int glo2 = lg ^ (l15 & 3);
  const int ghi2 = l15 & 12;
  const int wtail = l15*256 + ((((2*w + (lg>>1)) ^ l15)&15)<<4) + ((lg&1)<<3);
  const int slotW = lg*16 + (l15^lg);          // exchange slot (write & row-read)

  // resident C fragments, pre-scaled
  f32x4 Cf2[8];
  #pragma unroll
  for (int kt=0;kt<8;kt++)
    Cf2[kt] = -hscale * (*(const f32x4*)(Cb + (size_t)(16*kt+l15)*128 + n0));

  f32x4 lkR[8], lkC[8];
  float luR = 0.f, lvC = 0.f;

  // initial Sr staging (subsequent outers are prefetched during Sinkhorn)
  #pragma unroll
  for (int r2=0;r2<8;r2++)
    gload_lds16(SrHLb + r2*8192 + tid*16, bufS + r2*8192 + tid*16);

  for (int outer=0; outer<5; outer++){
    // ---- P0: T planes + avs; bvs via closed form
    {
      f32x4 avp = {0.f,0.f,0.f,0.f};
      #pragma unroll
      for (int q=0;q<8;q++){
        f32x4 TR;
        if (outer==0){
          const f32x4 nu4 = *(const f32x4*)(NUb + 16*q + 4*lg);
          TR = MUb[kR]*nu4;
        } else {
          const f32x4 lv4 = *(const f32x4*)&lvs[16*q + 4*lg];
          #pragma unroll
          for (int e=0;e<4;e++) TR[e] = exp2f(lkR[q][e] + luR + lv4[e]);
        }
        u16x4 hi4, lo4;
        #pragma unroll
        for (int e=0;e<4;e++){
          u16 h = f2b(TR[e]); hi4[e] = h;
          lo4[e] = f2b(TR[e] - b2f(h));
        }
        const int sa = kR*256 + ((((2*q+(lg>>1)) ^ l15)&15)<<4) + ((lg&1)<<3);
        *(u16x4*)(bufT + sa) = hi4;
        *(u16x4*)(bufT + 32768 + sa) = lo4;
        avp += TR;
      }
      float av = avp[0]+avp[1]+avp[2]+avp[3];
      av += __shfl_xor(av,16); av += __shfl_xor(av,32);
      if (lg==0){
        avs[kR] = av;
        // bv[n] = colsum(T) = exp2(lnu2_n - 10*eps*lv_n)  (exact; lv=0 at outer 0 -> nu)
        bvs[kR] = (outer==0) ? NUb[kR] : exp2f(lnu2C - 10.f*eps*lvC);
      }
    }
    __syncthreads();   // C: Sr planes (prefetched) + T planes + avs/bvs; drains vmcnt

    // ---- P1: t2 from Sr planes + bvs; phase A MFMA
    {
      const int p = tid>>2, sub = tid&3;
      float s2 = 0.f;
      #pragma unroll
      for (int gg=0; gg<4; gg++){
        const int g = 4*sub+gg;
        const int off = p*256 + (((g ^ (p&15))&15)<<4);
        const u16x8 h8 = *(const u16x8*)(bufS + off);
        const u16x8 l8 = *(const u16x8*)(bufS + 32768 + off);
        const f32x4 bva = *(const f32x4*)&bvs[8*g];
        const f32x4 bvb = *(const f32x4*)&bvs[8*g+4];
        #pragma unroll
        for (int e=0;e<4;e++){
          float x = b2f(h8[e]) + b2f(l8[e]);
          s2 = fmaf(bva[e], x*x, s2);
          float y2 = b2f(h8[4+e]) + b2f(l8[4+e]);
          s2 = fmaf(bvb[e], y2*y2, s2);
        }
      }
      s2 += __shfl_xor(s2,1); s2 += __shfl_xor(s2,2);
      if (sub==0) t2s[p] = s2;
    }
    f32x4 acc1[8] = {};
    #pragma unroll
    for (int qt=0;qt<4;qt++){
      const int colOff = (((4*qt) ^ ghi2) | glo2) << 4;
      const bf16x8 ahi = *(const bf16x8*)(bufT + rowA256 + colOff);
      const bf16x8 alo = *(const bf16x8*)(bufT + 32768 + rowA256 + colOff);
      const int bbase = l15*256 + colOff;
      #pragma unroll
      for (int nt=0;nt<8;nt++){
        const bf16x8 bhi = *(const bf16x8*)(bufS + nt*4096 + bbase);
        const bf16x8 blo = *(const bf16x8*)(bufS + 32768 + nt*4096 + bbase);
        acc1[nt] = __builtin_amdgcn_mfma_f32_16x16x32_bf16(ahi, bhi, acc1[nt], 0,0,0);
        acc1[nt] = __builtin_amdgcn_mfma_f32_16x16x32_bf16(ahi, blo, acc1[nt], 0,0,0);
        acc1[nt] = __builtin_amdgcn_mfma_f32_16x16x32_bf16(alo, bhi, acc1[nt], 0,0,0);
      }
    }
    __syncthreads();   // E

    // ---- P2: stage Sq; write TSr^T planes
    #pragma unroll
    for (int r2=0;r2<8;r2++)
      gload_lds16(SqHLb + r2*8192 + tid*16, bufS + r2*8192 + tid*16);
    #pragma unroll
    for (int nt=0;nt<8;nt++){
      u16x4 hi4, lo4;
      #pragma unroll
      for (int r=0;r<4;r++){
        u16 h = f2b(acc1[nt][r]); hi4[r] = h;
        lo4[r] = f2b(acc1[nt][r] - b2f(h));
      }
      const int sa = nt*4096 + wtail;
      *(u16x4*)(bufT + sa) = hi4;
      *(u16x4*)(bufT + 32768 + sa) = lo4;
    }
    __syncthreads();   // G: drains Sq prefetch + TSr^T planes

    // ---- P3: t1 from Sq planes + avs; phase B MFMA
    {
      const int p = tid>>2, sub = tid&3;
      float s1 = 0.f;
      #pragma unroll
      for (int gg=0; gg<4; gg++){
        const int g = 4*sub+gg;
        const int off = p*256 + (((g ^ (p&15))&15)<<4);
        const u16x8 h8 = *(const u16x8*)(bufS + off);
        const u16x8 l8 = *(const u16x8*)(bufS + 32768 + off);
        const f32x4 ava = *(const f32x4*)&avs[8*g];
        const f32x4 avb = *(const f32x4*)&avs[8*g+4];
        #pragma unroll
        for (int e=0;e<4;e++){
          float x = b2f(h8[e]) + b2f(l8[e]);
          s1 = fmaf(ava[e], x*x, s1);
          float y2 = b2f(h8[4+e]) + b2f(l8[4+e]);
          s1 = fmaf(avb[e], y2*y2, s1);
        }
      }
      s1 += __shfl_xor(s1,1); s1 += __shfl_xor(s1,2);
      if (sub==0) t1s[p] = s1;
    }
    f32x4 acc2[8] = {};
    #pragma unroll
    for (int qt=0;qt<4;qt++){
      const int colOff = (((4*qt) ^ ghi2) | glo2) << 4;
      const bf16x8 ahi = *(const bf16x8*)(bufT + rowA256 + colOff);
      const bf16x8 alo = *(const bf16x8*)(bufT + 32768 + rowA256 + colOff);
      const int bbase = l15*256 + colOff;
      #pragma unroll
      for (int kt=0;kt<8;kt++){
        const bf16x8 bhi = *(const bf16x8*)(bufS + kt*4096 + bbase);
        const bf16x8 blo = *(const bf16x8*)(bufS + 32768 + kt*4096 + bbase);
        acc2[kt] = __builtin_amdgcn_mfma_f32_16x16x32_bf16(ahi, bhi, acc2[kt], 0,0,0);
        acc2[kt] = __builtin_amdgcn_mfma_f32_16x16x32_bf16(ahi, blo, acc2[kt], 0,0,0);
        acc2[kt] = __builtin_amdgcn_mfma_f32_16x16x32_bf16(alo, bhi, acc2[kt], 0,0,0);
      }
    }
    __syncthreads();   // I: phase-B reads done; bufS free from here

    // ---- P4: prefetch next Sr (hidden under Sinkhorn); lk build + exchange
    if (outer<4){
      #pragma unroll
      for (int r2=0;r2<8;r2++)
        gload_lds16(SrHLb + r2*8192 + tid*16, bufS + r2*8192 + tid*16);
    }
    f32x4 lkf[8];
    {
      const f32x4 t24 = *(const f32x4*)&t2s[n0];
      #pragma unroll
      for (int kt=0;kt<8;kt++){
        const float t1v = t1s[16*kt+l15];
        lkf[kt] = Cf2[kt] + hscale*(2.0f*acc2[kt] - t1v - t24);
      }
    }
    // exchange buffer X[kt][w][slot] (f32x4), slot = lg*16 + (l15^lg)
    #pragma unroll
    for (int kt=0;kt<8;kt++)
      *(f32x4*)(bufT + (((kt*8+w)*64 + slotW)<<4)) = lkf[kt];
    lds_bar();         // K (lgkm-only; prefetch stays in flight)
    #pragma unroll
    for (int q=0;q<8;q++)
      lkR[q] = *(const f32x4*)(bufT + (((w*8+q)*64 + slotW)<<4));
    #pragma unroll
    for (int q=0;q<8;q++){
      #pragma unroll
      for (int e=0;e<4;e++){
        const int slotC = (l15>>2)*16 + ((4*lg+e) ^ (l15>>2));
        lkC[q][e] = *(const float*)(bufT + (((q*8+w)*64 + slotC)<<4) + ((l15&3)<<2));
      }
    }

    // ---- Sinkhorn: 10 iterations, base-2, lgkm-only barriers
    for (int it=0; it<10; it++){
      f32x4 y[8];
      #pragma unroll
      for (int q=0;q<8;q++){
        y[q] = lkR[q];
        if (it) y[q] += *(const f32x4*)&lvs[16*q+4*lg];
      }
      f32x4 m4 = vmax4(vmax4(vmax4(y[0],y[1]),vmax4(y[2],y[3])),
                       vmax4(vmax4(y[4],y[5]),vmax4(y[6],y[7])));
      float mx = fmaxf(fmaxf(m4[0],m4[1]), fmaxf(m4[2],m4[3]));
      mx = fmaxf(mx,__shfl_xor(mx,16)); mx = fmaxf(mx,__shfl_xor(mx,32));
      f32x4 s4 = {0.f,0.f,0.f,0.f};
      #pragma unroll
      for (int q=0;q<8;q++){
        #pragma unroll
        for (int e=0;e<4;e++) s4[e] += exp2f(y[q][e]-mx);
      }
      float s = s4[0]+s4[1]+s4[2]+s4[3];
      s += __shfl_xor(s,16); s += __shfl_xor(s,32);
      luR = rho*(lmu2R - (mx + __log2f(s)));
      if (lg==0) lus[kR] = luR;
      lds_bar();
      #pragma unroll
      for (int q=0;q<8;q++)
        y[q] = lkC[q] + *(const f32x4*)&lus[16*q+4*lg];
      m4 = vmax4(vmax4(vmax4(y[0],y[1]),vmax4(y[2],y[3])),
                 vmax4(vmax4(y[4],y[5]),vmax4(y[6],y[7])));
      mx = fmaxf(fmaxf(m4[0],m4[1]), fmaxf(m4[2],m4[3]));
      mx = fmaxf(mx,__shfl_xor(mx,16)); mx = fmaxf(mx,__shfl_xor(mx,32));
      s4 = (f32x4){0.f,0.f,0.f,0.f};
      #pragma unroll
      for (int q=0;q<8;q++){
        #pragma unroll
        for (int e=0;e<4;e++) s4[e] += exp2f(y[q][e]-mx);
      }
      s = s4[0]+s4[1]+s4[2]+s4[3];
      s += __shfl_xor(s,16); s += __shfl_xor(s,32);
      lvC = rho*(lnu2C - (mx + __log2f(s)));
      if (lg==0) lvs[kR] = lvC;
      lds_bar();
    }

    if (outer==4){
      float cp = 0.f;
      float* Tb = T_out + (size_t)b*16384;
      #pragma unroll
      for (int q=0;q<8;q++){
        const f32x4 lv4 = *(const f32x4*)&lvs[16*q+4*lg];
        f32x4 t;
        #pragma unroll
        for (int e=0;e<4;e++) t[e] = exp2f(lkR[q][e] + luR + lv4[e]);
        *(f32x4*)(Tb + kR*128 + 16*q + 4*lg) = t;
        const f32x4 pr = t*lkR[q];
        cp += pr[0]+pr[1]+pr[2]+pr[3];
      }
      cp *= -eps*0.6931471805599453f;
      #pragma unroll
      for (int off=1;off<64;off<<=1) cp += __shfl_xor(cp, off);
      if (lane==0) redc[w] = cp;
      __syncthreads();
      if (tid==0){
        float tot = 0.f;
        #pragma unroll
        for (int w2=0;w2<8;w2++) tot += redc[w2];
        cost_out[b] = tot;
        sim_out[b]  = 1.0f/(1.0f + __expf(tot));
      }
    }
  }
}

// ---------------------------------------------------------------------------
extern "C" void kernel_launch(void* const* d_in, const int* in_sizes, int n_in,
                              void* d_out, int out_size, void* d_ws, size_t ws_size,
                              hipStream_t stream){
  const float* sq      = (const float*)d_in[0];
  const float* sr      = (const float*)d_in[1];
  const float* mask_q  = (const float*)d_in[2];
  const float* mask_r  = (const float*)d_in[3];
  const float* cq      = (const float*)d_in[4];
  const float* cr      = (const float*)d_in[5];
  const float* W1      = (const float*)d_in[6];
  const float* b1      = (const float*)d_in[7];
  const float* W2      = (const float*)d_in[8];
  const float* b2      = (const float*)d_in[9];
  const float* log_eps = (const float*)d_in[10];

  float* out  = (float*)d_out;
  float* sim  = out;                 // [256]
  float* Tm   = out + 256;           // [256][128][128]
  float* Cm   = Tm + 4194304;        // [256][128][128]
  float* cost = Cm + 4194304;        // [256]

  char* ws = (char*)d_ws;
  size_t off = 0;
  auto alloc = [&](size_t bytes)->void*{ void* p = ws + off; off += (bytes+255)&~(size_t)255; return p; };
  u16*   PQ  = (u16*)  alloc(67108864);   // P bf16 (65536x512); later loop planes
  u16*   HQ  = (u16*)  alloc(67108864);   // hidden H bf16 (65536x512)
  u16*   W1T = (u16*)  alloc(524288);
  u16*   W2T = (u16*)  alloc(524288);
  float* NP  = (float*)alloc(262144);     // row norms of P (65536)
  float* LMU = (float*)alloc(131072);
  float* LNU = (float*)alloc(131072);
  float* MUA = (float*)alloc(131072);
  float* NUA = (float*)alloc(131072);
  (void)ws_size; (void)in_sizes; (void)n_in; (void)out_size;

  char* SQHL = (char*)PQ;                  // 16MB bf16 hi/lo Sq planes
  char* SRHL = (char*)PQ + 16777216;       // 16MB bf16 hi/lo Sr planes

  prologue_k<<<2176,256,0,stream>>>(W1, W2, W1T, W2T, mask_q, mask_r,
                                    LMU, LNU, MUA, NUA);
  gemm_k<1,0,1><<<2048,256,0,stream>>>(nullptr, sq, sr, W1T, b1, HQ, nullptr);
  hipMemsetAsync(NP, 0, 262144, stream);
  gemm_k<0,1,0><<<2048,256,0,stream>>>(HQ, nullptr, nullptr, W2T, b2, PQ, NP);
  pdist0_k<<<256,256,0,stream>>>(PQ, PQ + (size_t)32768*512, NP, NP + 32768, Cm);
  pdistS2_k<<<512,256,0,stream>>>(cq, cr, SQHL, SRHL);
  prep_dummy: ;
  fgw_loop_k<<<256,512,0,stream>>>(SQHL, SRHL, Cm, MUA, NUA, LMU, LNU,
                                   log_eps, Tm, cost, sim);
}

// Round 10
// 412.877 us; speedup vs baseline: 1.3105x; 1.0539x over previous
//
#include <hip/hip_runtime.h>
#include <math.h>

typedef unsigned short u16;
typedef __attribute__((ext_vector_type(4))) float f32x4;
typedef __attribute__((ext_vector_type(8))) short bf16x8;
typedef __attribute__((ext_vector_type(4))) unsigned short u16x4;
typedef __attribute__((ext_vector_type(8))) unsigned short u16x8;

#define DEVI static __device__ __forceinline__

DEVI float b2f(u16 u){ union{float f; unsigned i;} v; v.i = ((unsigned)u)<<16; return v.f; }
DEVI u16 f2b(float f){ union{float f; unsigned i;} v; v.f=f;
  unsigned r = v.i + 0x7fffu + ((v.i>>16)&1u); return (u16)(r>>16); }

DEVI void gload_lds16(const void* g, void* l){
  __builtin_amdgcn_global_load_lds((const __attribute__((address_space(1))) void*)g,
                                   (__attribute__((address_space(3))) void*)l, 16, 0, 0);
}

// LDS-only barrier: waits DS ops, does NOT drain vmcnt (keeps prefetch in flight)
DEVI void lds_bar(){ asm volatile("s_waitcnt lgkmcnt(0)\n\ts_barrier" ::: "memory"); }

DEVI f32x4 vmax4(f32x4 a, f32x4 b){
  f32x4 r; r[0]=fmaxf(a[0],b[0]); r[1]=fmaxf(a[1],b[1]);
  r[2]=fmaxf(a[2],b[2]); r[3]=fmaxf(a[3],b[3]); return r;
}

// ---------------------------------------------------------------------------
// Merged prologue: blocks [0,2048): W1/W2 -> bf16 [c][k]; blocks [2048,2176):
// mu/nu + base-2 logs (2 batches per 256-thread block).
__global__ void prologue_k(const float* __restrict__ W1, const float* __restrict__ W2,
                           u16* __restrict__ W1T, u16* __restrict__ W2T,
                           const float* __restrict__ mask_q, const float* __restrict__ mask_r,
                           float* __restrict__ lmu2, float* __restrict__ lnu2,
                           float* __restrict__ mu, float* __restrict__ nu){
  const int blk = blockIdx.x;
  if (blk < 2048){
    const float* W = (blk<1024)? W1 : W2;
    u16* Wt = (blk<1024)? W1T : W2T;
    int id = (blk&1023)*256 + threadIdx.x;
    int k = id>>9, c = id&511;
    Wt[c*512 + k] = f2b(W[id]);
  } else {
    __shared__ float red[2][4];
    const int h = threadIdx.x>>7, t = threadIdx.x&127;
    const int b = (blk-2048)*2 + h;
    float mq = mask_q[b*128+t], mr = mask_r[b*128+t];
    float s1 = mq, s2 = mr;
    #pragma unroll
    for (int off=1;off<64;off<<=1){ s1 += __shfl_xor(s1,off); s2 += __shfl_xor(s2,off); }
    if ((t&63)==0){ red[h][(t>>6)&1] = s1; red[h][2+((t>>6)&1)] = s2; }
    __syncthreads();
    float sumq = red[h][0]+red[h][1], sumr = red[h][2]+red[h][3];
    float muv = mq/(sumq+1e-8f), nuv = mr/(sumr+1e-8f);
    lmu2[b*128+t] = __log2f(fmaxf(muv,1e-8f));
    lnu2[b*128+t] = __log2f(fmaxf(nuv,1e-8f));
    mu[b*128+t] = muv;
    nu[b*128+t] = nuv;
  }
}

// ---------------------------------------------------------------------------
// OUT[r][c] = act(sum_k X[r][k]*W[k][c] + bias[c]); Wt bf16 [c][k].
// AF32: A-tile reg-staged from f32 sources. NORM: per-cb row-norm partials
// written non-atomically to NP4[cb][row]. Epilogue via LDS transpose:
// 128x140-u16 buffer, coalesced 16B row stores.
template<int ACT, int NORM, int AF32>
__global__ __launch_bounds__(256) void gemm_k(const u16* __restrict__ X,
    const float* __restrict__ Xf1, const float* __restrict__ Xf2,
    const u16* __restrict__ Wt, const float* __restrict__ bias, u16* __restrict__ OUT,
    float* __restrict__ NP4){
  __shared__ __align__(16) u16 smem[17920];    // K-loop: sA[0,8192) sB[8192,16384); epi: 128x140
  u16* sA = smem;
  u16* sB = smem + 8192;
  const int tid = threadIdx.x, wave = tid>>6, lane = tid&63;
  const int bid = (blockIdx.x&7)*256 + (blockIdx.x>>3);
  const int rblk = bid>>2, cb = (bid&3)<<7;
  const u16* Xb = AF32 ? nullptr : (X + (size_t)rblk*(128*512));
  const float* Xbf = AF32 ? (rblk<256 ? Xf1 + (size_t)rblk*65536
                                      : Xf2 + (size_t)(rblk-256)*65536) : nullptr;
  const u16* Wb = Wt + (size_t)cb*512;
  const int lrow = lane&15, lg = lane>>4, wr = wave>>1, wc = wave&1;
  f32x4 acc[4][4] = {};
  for (int s=0;s<8;s++){
    const int k0 = s<<6;
    #pragma unroll
    for (int q=0;q<4;q++){
      const int i = (wave<<2)+q;
      const int row = (i<<3) + (lane>>3);
      const int cd = (lane&7) ^ (row&7);
      if (AF32){
        const float* src = Xbf + row*512 + k0 + (cd<<3);
        const f32x4 va = *(const f32x4*)src;
        const f32x4 vb = *(const f32x4*)(src+4);
        u16x8 t;
        #pragma unroll
        for (int e=0;e<4;e++){ t[e]=f2b(va[e]); t[4+e]=f2b(vb[e]); }
        *(u16x8*)((char*)sA + i*1024 + lane*16) = t;
      } else {
        gload_lds16(Xb + row*512 + k0 + (cd<<3), sA + i*512);
      }
      gload_lds16(Wb + row*512 + k0 + (cd<<3), sB + i*512);
    }
    __syncthreads();
    #pragma unroll
    for (int kh=0;kh<2;kh++){
      bf16x8 a_[4], b_[4];
      #pragma unroll
      for (int i=0;i<4;i++){
        const int ra = (wr<<6)+(i<<4)+lrow;
        a_[i] = *(const bf16x8*)(sA + ra*64 + ((((kh<<2)+lg)^(ra&7))<<3));
        const int rb = (wc<<6)+(i<<4)+lrow;
        b_[i] = *(const bf16x8*)(sB + rb*64 + ((((kh<<2)+lg)^(rb&7))<<3));
      }
      #pragma unroll
      for (int i=0;i<4;i++)
        #pragma unroll
        for (int j=0;j<4;j++)
          acc[i][j] = __builtin_amdgcn_mfma_f32_16x16x32_bf16(a_[i], b_[j], acc[i][j], 0,0,0);
    }
    __syncthreads();
  }
  // ---- epilogue: bias+act+cvt -> LDS (stride 140 u16), coalesced readback
  #pragma unroll
  for (int j=0;j<4;j++){
    const int colb = (wc<<6) + (j<<4) + lrow;
    const float bv = bias[cb + colb];
    #pragma unroll
    for (int i=0;i<4;i++){
      const int rowb = (wr<<6)+(i<<4)+(lg<<2);
      #pragma unroll
      for (int r=0;r<4;r++){
        float v = acc[i][j][r] + bv;
        if (ACT) v = fmaxf(v, 0.f);
        smem[(rowb+r)*140 + colb] = f2b(v);
      }
    }
  }
  __syncthreads();
  const int chunk = lane&15, rql = lane>>4;
  float ns[8];
  #pragma unroll
  for (int it=0; it<8; it++){
    const int rowb = it*16 + wave*4 + rql;
    u16x8 v8 = *(const u16x8*)(smem + rowb*140 + chunk*8);
    *(u16x8*)(OUT + (size_t)((rblk<<7)+rowb)*512 + cb + chunk*8) = v8;
    if (NORM){
      float s = 0.f;
      #pragma unroll
      for (int e=0;e<8;e++){ float f = b2f(v8[e]); s = fmaf(f,f,s); }
      s += __shfl_xor(s,1); s += __shfl_xor(s,2);
      s += __shfl_xor(s,4); s += __shfl_xor(s,8);
      ns[it] = s;
    }
  }
  if (NORM && chunk==0){
    #pragma unroll
    for (int it=0;it<8;it++)
      NP4[(size_t)(bid&3)*65536 + (rblk<<7) + it*16 + wave*4 + rql] = ns[it];
  }
}

// ---------------------------------------------------------------------------
// pdist_all: 768 blocks.
//  [0,256):   C[b] from P rows (norms = sum of NP4 partials)
//  [256,512): Sq hi/lo planes from cq (f32 reg-staged, self-norms)
//  [512,768): Sr hi/lo planes from cr
__global__ __launch_bounds__(256) void pdist_all_k(const u16* __restrict__ PQ,
    const float* __restrict__ NP4, const float* __restrict__ cq,
    const float* __restrict__ cr, float* __restrict__ Cm,
    char* __restrict__ SQHL, char* __restrict__ SRHL){
  __shared__ __align__(16) u16 sA[8192];
  __shared__ __align__(16) u16 sB[8192];
  __shared__ float nA[128], nB[128];
  const int tid = threadIdx.x, wave = tid>>6, lane = tid&63;
  const int lrow = lane&15, lg = lane>>4, wr = wave>>1, wc = wave&1;
  const int b = blockIdx.x & 255;

  if (blockIdx.x < 256){
    // ---- pdist0 role
    if (tid < 128){
      const int row = b*128 + tid;
      nA[tid] = NP4[row] + NP4[65536+row] + NP4[131072+row] + NP4[196608+row];
    } else {
      const int row = 32768 + b*128 + (tid-128);
      nB[tid-128] = NP4[row] + NP4[65536+row] + NP4[131072+row] + NP4[196608+row];
    }
    const u16* Ab = PQ + (size_t)b*(128*512);
    const u16* Bb = PQ + (size_t)(32768 + b*128)*512;
    f32x4 acc[4][4] = {};
    for (int s=0;s<8;s++){
      const int k0 = s<<6;
      #pragma unroll
      for (int q=0;q<4;q++){
        const int i = (wave<<2)+q;
        const int row = (i<<3) + (lane>>3);
        const int cd = (lane&7) ^ (row&7);
        gload_lds16(Ab + row*512 + k0 + (cd<<3), sA + i*512);
        gload_lds16(Bb + row*512 + k0 + (cd<<3), sB + i*512);
      }
      __syncthreads();
      #pragma unroll
      for (int kh=0;kh<2;kh++){
        bf16x8 a_[4], b_[4];
        #pragma unroll
        for (int i=0;i<4;i++){
          const int ra = (wr<<6)+(i<<4)+lrow;
          a_[i] = *(const bf16x8*)(sA + ra*64 + ((((kh<<2)+lg)^(ra&7))<<3));
          const int rb = (wc<<6)+(i<<4)+lrow;
          b_[i] = *(const bf16x8*)(sB + rb*64 + ((((kh<<2)+lg)^(rb&7))<<3));
        }
        #pragma unroll
        for (int i=0;i<4;i++)
          #pragma unroll
          for (int j=0;j<4;j++)
            acc[i][j] = __builtin_amdgcn_mfma_f32_16x16x32_bf16(a_[i], b_[j], acc[i][j], 0,0,0);
      }
      __syncthreads();
    }
    #pragma unroll
    for (int j=0;j<4;j++){
      const int col = (wc<<6)+(j<<4)+lrow;
      const float nbv = nB[col];
      #pragma unroll
      for (int i=0;i<4;i++){
        const int row0 = (wr<<6)+(i<<4)+(lg<<2);
        #pragma unroll
        for (int r=0;r<4;r++){
          float n2 = nA[row0+r] + nbv - 2.0f*acc[i][j][r];
          Cm[(size_t)b*16384 + (size_t)(row0+r)*128 + col] = sqrtf(fmaxf(n2, 1e-6f));
        }
      }
    }
  } else {
    // ---- pdistS role (symmetric; single LDS buffer; norms during staging)
    const float* Sb = ((blockIdx.x < 512)? cq : cr) + (size_t)b*65536;
    char* SHL = (blockIdx.x < 512)? SQHL : SRHL;
    f32x4 acc[4][4] = {};
    float nacc[4] = {0.f,0.f,0.f,0.f};
    for (int s=0;s<8;s++){
      const int k0 = s<<6;
      #pragma unroll
      for (int q=0;q<4;q++){
        const int i = (wave<<2)+q;
        const int row = (i<<3) + (lane>>3);
        const int cd = (lane&7) ^ (row&7);
        const float* src = Sb + row*512 + k0 + (cd<<3);
        const f32x4 va = *(const f32x4*)src;
        const f32x4 vb = *(const f32x4*)(src+4);
        u16x8 t;
        #pragma unroll
        for (int e=0;e<4;e++){ t[e]=f2b(va[e]); t[4+e]=f2b(vb[e]); }
        #pragma unroll
        for (int e=0;e<8;e++){ float fv=b2f(t[e]); nacc[q]=fmaf(fv,fv,nacc[q]); }
        *(u16x8*)((char*)sA + i*1024 + lane*16) = t;
      }
      __syncthreads();
      #pragma unroll
      for (int kh=0;kh<2;kh++){
        bf16x8 a_[4], b_[4];
        #pragma unroll
        for (int i=0;i<4;i++){
          const int ra = (wr<<6)+(i<<4)+lrow;
          a_[i] = *(const bf16x8*)(sA + ra*64 + ((((kh<<2)+lg)^(ra&7))<<3));
          const int rb = (wc<<6)+(i<<4)+lrow;
          b_[i] = *(const bf16x8*)(sA + rb*64 + ((((kh<<2)+lg)^(rb&7))<<3));
        }
        #pragma unroll
        for (int i=0;i<4;i++)
          #pragma unroll
          for (int j=0;j<4;j++)
            acc[i][j] = __builtin_amdgcn_mfma_f32_16x16x32_bf16(a_[i], b_[j], acc[i][j], 0,0,0);
      }
      __syncthreads();
    }
    #pragma unroll
    for (int q=0;q<4;q++){
      float v = nacc[q];
      v += __shfl_xor(v,1); v += __shfl_xor(v,2); v += __shfl_xor(v,4);
      if ((lane&7)==0) nA[((wave<<2)+q)*8 + (lane>>3)] = v;
    }
    __syncthreads();
    #pragma unroll
    for (int j=0;j<4;j++){
      const int col = (wc<<6)+(j<<4)+lrow;
      const float nbv = nA[col];
      #pragma unroll
      for (int i=0;i<4;i++){
        const int row0 = (wr<<6)+(i<<4)+(lg<<2);
        u16x4 hi4, lo4;
        #pragma unroll
        for (int r=0;r<4;r++){
          float n2 = nA[row0+r] + nbv - 2.0f*acc[i][j][r];
          float sv = sqrtf(fmaxf(n2, 1e-6f));
          u16 h = f2b(sv); hi4[r] = h;
          lo4[r] = f2b(sv - b2f(h));
        }
        const int sa = col*256 + ((((row0>>3)^col)&15)<<4) + ((row0&7)<<1);
        char* base = SHL + (size_t)b*65536;
        *(u16x4*)(base + sa) = hi4;
        *(u16x4*)(base + 32768 + sa) = lo4;
      }
    }
  }
}

// ---------------------------------------------------------------------------
// 5-iter FGW loop, 512 threads/block, base-2 log-domain Sinkhorn.
// (unchanged from R8 — verified twice)
__global__ __launch_bounds__(512,1) void fgw_loop_k(
    const char* __restrict__ SQHL, const char* __restrict__ SRHL,
    const float* __restrict__ C_g,
    const float* __restrict__ MU, const float* __restrict__ NU,
    const float* __restrict__ LMU2, const float* __restrict__ LNU2,
    const float* __restrict__ log_eps,
    float* __restrict__ T_out, float* __restrict__ cost_out, float* __restrict__ sim_out)
{
  __shared__ __align__(16) char bufT[65536];
  __shared__ __align__(16) char bufS[65536];
  __shared__ __align__(16) float avs[128], bvs[128], t1s[128], t2s[128];
  __shared__ __align__(16) float lus[128], lvs[128];
  __shared__ float redc[8];

  const int b = blockIdx.x, tid = threadIdx.x;
  const int w = tid>>6, lane = tid&63, l15 = lane&15, lg = lane>>4;
  const char* SqHLb = SQHL + (size_t)b*65536;
  const char* SrHLb = SRHL + (size_t)b*65536;
  const float* Cb   = C_g + (size_t)b*16384;
  const float* MUb  = MU + b*128;
  const float* NUb  = NU + b*128;

  float eps = __expf(log_eps[0]); eps = fminf(fmaxf(eps,0.01f),0.5f);
  const float rho = 0.1f/(0.1f+eps);
  const float hscale = 0.5f*1.4426950408889634f/eps;

  const int kR = 16*w + l15;
  const int n0 = 16*w + 4*lg;
  const float lmu2R = LMU2[b*128+kR];
  const float lnu2C = LNU2[b*128+kR];

  const int rowA256 = (16*w + l15)*256;
  const int glo2 = lg ^ (l15 & 3);
  const int ghi2 = l15 & 12;
  const int wtail = l15*256 + ((((2*w + (lg>>1)) ^ l15)&15)<<4) + ((lg&1)<<3);
  const int slotW = lg*16 + (l15^lg);

  f32x4 Cf2[8];
  #pragma unroll
  for (int kt=0;kt<8;kt++)
    Cf2[kt] = -hscale * (*(const f32x4*)(Cb + (size_t)(16*kt+l15)*128 + n0));

  f32x4 lkR[8], lkC[8];
  float luR = 0.f, lvC = 0.f;

  #pragma unroll
  for (int r2=0;r2<8;r2++)
    gload_lds16(SrHLb + r2*8192 + tid*16, bufS + r2*8192 + tid*16);

  for (int outer=0; outer<5; outer++){
    // ---- P0: T planes + avs; bvs via closed form
    {
      f32x4 avp = {0.f,0.f,0.f,0.f};
      #pragma unroll
      for (int q=0;q<8;q++){
        f32x4 TR;
        if (outer==0){
          const f32x4 nu4 = *(const f32x4*)(NUb + 16*q + 4*lg);
          TR = MUb[kR]*nu4;
        } else {
          const f32x4 lv4 = *(const f32x4*)&lvs[16*q + 4*lg];
          #pragma unroll
          for (int e=0;e<4;e++) TR[e] = exp2f(lkR[q][e] + luR + lv4[e]);
        }
        u16x4 hi4, lo4;
        #pragma unroll
        for (int e=0;e<4;e++){
          u16 h = f2b(TR[e]); hi4[e] = h;
          lo4[e] = f2b(TR[e] - b2f(h));
        }
        const int sa = kR*256 + ((((2*q+(lg>>1)) ^ l15)&15)<<4) + ((lg&1)<<3);
        *(u16x4*)(bufT + sa) = hi4;
        *(u16x4*)(bufT + 32768 + sa) = lo4;
        avp += TR;
      }
      float av = avp[0]+avp[1]+avp[2]+avp[3];
      av += __shfl_xor(av,16); av += __shfl_xor(av,32);
      if (lg==0){
        avs[kR] = av;
        bvs[kR] = (outer==0) ? NUb[kR] : exp2f(lnu2C - 10.f*eps*lvC);
      }
    }
    __syncthreads();

    // ---- P1: t2 from Sr planes + bvs; phase A MFMA
    {
      const int p = tid>>2, sub = tid&3;
      float s2 = 0.f;
      #pragma unroll
      for (int gg=0; gg<4; gg++){
        const int g = 4*sub+gg;
        const int off = p*256 + (((g ^ (p&15))&15)<<4);
        const u16x8 h8 = *(const u16x8*)(bufS + off);
        const u16x8 l8 = *(const u16x8*)(bufS + 32768 + off);
        const f32x4 bva = *(const f32x4*)&bvs[8*g];
        const f32x4 bvb = *(const f32x4*)&bvs[8*g+4];
        #pragma unroll
        for (int e=0;e<4;e++){
          float x = b2f(h8[e]) + b2f(l8[e]);
          s2 = fmaf(bva[e], x*x, s2);
          float y2 = b2f(h8[4+e]) + b2f(l8[4+e]);
          s2 = fmaf(bvb[e], y2*y2, s2);
        }
      }
      s2 += __shfl_xor(s2,1); s2 += __shfl_xor(s2,2);
      if (sub==0) t2s[p] = s2;
    }
    f32x4 acc1[8] = {};
    #pragma unroll
    for (int qt=0;qt<4;qt++){
      const int colOff = (((4*qt) ^ ghi2) | glo2) << 4;
      const bf16x8 ahi = *(const bf16x8*)(bufT + rowA256 + colOff);
      const bf16x8 alo = *(const bf16x8*)(bufT + 32768 + rowA256 + colOff);
      const int bbase = l15*256 + colOff;
      #pragma unroll
      for (int nt=0;nt<8;nt++){
        const bf16x8 bhi = *(const bf16x8*)(bufS + nt*4096 + bbase);
        const bf16x8 blo = *(const bf16x8*)(bufS + 32768 + nt*4096 + bbase);
        acc1[nt] = __builtin_amdgcn_mfma_f32_16x16x32_bf16(ahi, bhi, acc1[nt], 0,0,0);
        acc1[nt] = __builtin_amdgcn_mfma_f32_16x16x32_bf16(ahi, blo, acc1[nt], 0,0,0);
        acc1[nt] = __builtin_amdgcn_mfma_f32_16x16x32_bf16(alo, bhi, acc1[nt], 0,0,0);
      }
    }
    __syncthreads();

    // ---- P2: stage Sq; write TSr^T planes
    #pragma unroll
    for (int r2=0;r2<8;r2++)
      gload_lds16(SqHLb + r2*8192 + tid*16, bufS + r2*8192 + tid*16);
    #pragma unroll
    for (int nt=0;nt<8;nt++){
      u16x4 hi4, lo4;
      #pragma unroll
      for (int r=0;r<4;r++){
        u16 h = f2b(acc1[nt][r]); hi4[r] = h;
        lo4[r] = f2b(acc1[nt][r] - b2f(h));
      }
      const int sa = nt*4096 + wtail;
      *(u16x4*)(bufT + sa) = hi4;
      *(u16x4*)(bufT + 32768 + sa) = lo4;
    }
    __syncthreads();

    // ---- P3: t1 from Sq planes + avs; phase B MFMA
    {
      const int p = tid>>2, sub = tid&3;
      float s1 = 0.f;
      #pragma unroll
      for (int gg=0; gg<4; gg++){
        const int g = 4*sub+gg;
        const int off = p*256 + (((g ^ (p&15))&15)<<4);
        const u16x8 h8 = *(const u16x8*)(bufS + off);
        const u16x8 l8 = *(const u16x8*)(bufS + 32768 + off);
        const f32x4 ava = *(const f32x4*)&avs[8*g];
        const f32x4 avb = *(const f32x4*)&avs[8*g+4];
        #pragma unroll
        for (int e=0;e<4;e++){
          float x = b2f(h8[e]) + b2f(l8[e]);
          s1 = fmaf(ava[e], x*x, s1);
          float y2 = b2f(h8[4+e]) + b2f(l8[4+e]);
          s1 = fmaf(avb[e], y2*y2, s1);
        }
      }
      s1 += __shfl_xor(s1,1); s1 += __shfl_xor(s1,2);
      if (sub==0) t1s[p] = s1;
    }
    f32x4 acc2[8] = {};
    #pragma unroll
    for (int qt=0;qt<4;qt++){
      const int colOff = (((4*qt) ^ ghi2) | glo2) << 4;
      const bf16x8 ahi = *(const bf16x8*)(bufT + rowA256 + colOff);
      const bf16x8 alo = *(const bf16x8*)(bufT + 32768 + rowA256 + colOff);
      const int bbase = l15*256 + colOff;
      #pragma unroll
      for (int kt=0;kt<8;kt++){
        const bf16x8 bhi = *(const bf16x8*)(bufS + kt*4096 + bbase);
        const bf16x8 blo = *(const bf16x8*)(bufS + 32768 + kt*4096 + bbase);
        acc2[kt] = __builtin_amdgcn_mfma_f32_16x16x32_bf16(ahi, bhi, acc2[kt], 0,0,0);
        acc2[kt] = __builtin_amdgcn_mfma_f32_16x16x32_bf16(ahi, blo, acc2[kt], 0,0,0);
        acc2[kt] = __builtin_amdgcn_mfma_f32_16x16x32_bf16(alo, bhi, acc2[kt], 0,0,0);
      }
    }
    __syncthreads();

    // ---- P4: prefetch next Sr; lk build + exchange
    if (outer<4){
      #pragma unroll
      for (int r2=0;r2<8;r2++)
        gload_lds16(SrHLb + r2*8192 + tid*16, bufS + r2*8192 + tid*16);
    }
    f32x4 lkf[8];
    {
      const f32x4 t24 = *(const f32x4*)&t2s[n0];
      #pragma unroll
      for (int kt=0;kt<8;kt++){
        const float t1v = t1s[16*kt+l15];
        lkf[kt] = Cf2[kt] + hscale*(2.0f*acc2[kt] - t1v - t24);
      }
    }
    #pragma unroll
    for (int kt=0;kt<8;kt++)
      *(f32x4*)(bufT + (((kt*8+w)*64 + slotW)<<4)) = lkf[kt];
    lds_bar();
    #pragma unroll
    for (int q=0;q<8;q++)
      lkR[q] = *(const f32x4*)(bufT + (((w*8+q)*64 + slotW)<<4));
    #pragma unroll
    for (int q=0;q<8;q++){
      #pragma unroll
      for (int e=0;e<4;e++){
        const int slotC = (l15>>2)*16 + ((4*lg+e) ^ (l15>>2));
        lkC[q][e] = *(const float*)(bufT + (((q*8+w)*64 + slotC)<<4) + ((l15&3)<<2));
      }
    }

    // ---- Sinkhorn: 10 iterations, base-2, lgkm-only barriers
    for (int it=0; it<10; it++){
      f32x4 y[8];
      #pragma unroll
      for (int q=0;q<8;q++){
        y[q] = lkR[q];
        if (it) y[q] += *(const f32x4*)&lvs[16*q+4*lg];
      }
      f32x4 m4 = vmax4(vmax4(vmax4(y[0],y[1]),vmax4(y[2],y[3])),
                       vmax4(vmax4(y[4],y[5]),vmax4(y[6],y[7])));
      float mx = fmaxf(fmaxf(m4[0],m4[1]), fmaxf(m4[2],m4[3]));
      mx = fmaxf(mx,__shfl_xor(mx,16)); mx = fmaxf(mx,__shfl_xor(mx,32));
      f32x4 s4 = {0.f,0.f,0.f,0.f};
      #pragma unroll
      for (int q=0;q<8;q++){
        #pragma unroll
        for (int e=0;e<4;e++) s4[e] += exp2f(y[q][e]-mx);
      }
      float s = s4[0]+s4[1]+s4[2]+s4[3];
      s += __shfl_xor(s,16); s += __shfl_xor(s,32);
      luR = rho*(lmu2R - (mx + __log2f(s)));
      if (lg==0) lus[kR] = luR;
      lds_bar();
      #pragma unroll
      for (int q=0;q<8;q++)
        y[q] = lkC[q] + *(const f32x4*)&lus[16*q+4*lg];
      m4 = vmax4(vmax4(vmax4(y[0],y[1]),vmax4(y[2],y[3])),
                 vmax4(vmax4(y[4],y[5]),vmax4(y[6],y[7])));
      mx = fmaxf(fmaxf(m4[0],m4[1]), fmaxf(m4[2],m4[3]));
      mx = fmaxf(mx,__shfl_xor(mx,16)); mx = fmaxf(mx,__shfl_xor(mx,32));
      s4 = (f32x4){0.f,0.f,0.f,0.f};
      #pragma unroll
      for (int q=0;q<8;q++){
        #pragma unroll
        for (int e=0;e<4;e++) s4[e] += exp2f(y[q][e]-mx);
      }
      s = s4[0]+s4[1]+s4[2]+s4[3];
      s += __shfl_xor(s,16); s += __shfl_xor(s,32);
      lvC = rho*(lnu2C - (mx + __log2f(s)));
      if (lg==0) lvs[kR] = lvC;
      lds_bar();
    }

    if (outer==4){
      float cp = 0.f;
      float* Tb = T_out + (size_t)b*16384;
      #pragma unroll
      for (int q=0;q<8;q++){
        const f32x4 lv4 = *(const f32x4*)&lvs[16*q+4*lg];
        f32x4 t;
        #pragma unroll
        for (int e=0;e<4;e++) t[e] = exp2f(lkR[q][e] + luR + lv4[e]);
        *(f32x4*)(Tb + kR*128 + 16*q + 4*lg) = t;
        const f32x4 pr = t*lkR[q];
        cp += pr[0]+pr[1]+pr[2]+pr[3];
      }
      cp *= -eps*0.6931471805599453f;
      #pragma unroll
      for (int off=1;off<64;off<<=1) cp += __shfl_xor(cp, off);
      if (lane==0) redc[w] = cp;
      __syncthreads();
      if (tid==0){
        float tot = 0.f;
        #pragma unroll
        for (int w2=0;w2<8;w2++) tot += redc[w2];
        cost_out[b] = tot;
        sim_out[b]  = 1.0f/(1.0f + __expf(tot));
      }
    }
  }
}

// ---------------------------------------------------------------------------
extern "C" void kernel_launch(void* const* d_in, const int* in_sizes, int n_in,
                              void* d_out, int out_size, void* d_ws, size_t ws_size,
                              hipStream_t stream){
  const float* sq      = (const float*)d_in[0];
  const float* sr      = (const float*)d_in[1];
  const float* mask_q  = (const float*)d_in[2];
  const float* mask_r  = (const float*)d_in[3];
  const float* cq      = (const float*)d_in[4];
  const float* cr      = (const float*)d_in[5];
  const float* W1      = (const float*)d_in[6];
  const float* b1      = (const float*)d_in[7];
  const float* W2      = (const float*)d_in[8];
  const float* b2      = (const float*)d_in[9];
  const float* log_eps = (const float*)d_in[10];

  float* out  = (float*)d_out;
  float* sim  = out;                 // [256]
  float* Tm   = out + 256;           // [256][128][128]
  float* Cm   = Tm + 4194304;        // [256][128][128]
  float* cost = Cm + 4194304;        // [256]

  char* ws = (char*)d_ws;
  size_t off = 0;
  auto alloc = [&](size_t bytes)->void*{ void* p = ws + off; off += (bytes+255)&~(size_t)255; return p; };
  u16*   PQ  = (u16*)  alloc(67108864);   // P bf16 (65536x512); later loop planes
  u16*   HQ  = (u16*)  alloc(67108864);   // hidden H bf16 (65536x512)
  u16*   W1T = (u16*)  alloc(524288);
  u16*   W2T = (u16*)  alloc(524288);
  float* NP4 = (float*)alloc(1048576);    // per-cb row-norm partials [4][65536]
  float* LMU = (float*)alloc(131072);
  float* LNU = (float*)alloc(131072);
  float* MUA = (float*)alloc(131072);
  float* NUA = (float*)alloc(131072);
  (void)ws_size; (void)in_sizes; (void)n_in; (void)out_size;

  char* SQHL = (char*)PQ;                  // 16MB bf16 hi/lo Sq planes
  char* SRHL = (char*)PQ + 16777216;       // 16MB bf16 hi/lo Sr planes

  prologue_k<<<2176,256,0,stream>>>(W1, W2, W1T, W2T, mask_q, mask_r,
                                    LMU, LNU, MUA, NUA);
  gemm_k<1,0,1><<<2048,256,0,stream>>>(nullptr, sq, sr, W1T, b1, HQ, nullptr);
  gemm_k<0,1,0><<<2048,256,0,stream>>>(HQ, nullptr, nullptr, W2T, b2, PQ, NP4);
  pdist_all_k<<<768,256,0,stream>>>(PQ, NP4, cq, cr, Cm, SQHL, SRHL);
  fgw_loop_k<<<256,512,0,stream>>>(SQHL, SRHL, Cm, MUA, NUA, LMU, LNU,
                                   log_eps, Tm, cost, sim);
}